// Round 1
// baseline (578.579 us; speedup 1.0000x reference)
//
#include <hip/hip_runtime.h>
#include <hip/hip_bf16.h>
#include <math.h>

// ---------- constants ----------
#define BB 2
#define TT 2048
#define DMODEL 2048
#define NH 16
#define NKV 4
#define DH 128
#define NQKV 3072            // 2048 + 512 + 512
#define MM (BB*TT)           // 4096

typedef unsigned short u16;
typedef unsigned int u32;

typedef __bf16 bf16x8 __attribute__((ext_vector_type(8)));
typedef float f32x4 __attribute__((ext_vector_type(4)));

__device__ __forceinline__ u16 f2b(float f) {
  union { float f; u32 u; } v; v.f = f;
  u32 r = v.u + 0x7fffu + ((v.u >> 16) & 1u);
  return (u16)(r >> 16);
}
__device__ __forceinline__ float b2f(u16 h) {
  union { u32 u; float f; } v; v.u = ((u32)h) << 16;
  return v.f;
}

// async global->LDS, 16B per lane
__device__ __forceinline__ void gload16(const void* g, void* l) {
  __builtin_amdgcn_global_load_lds(
      (const __attribute__((address_space(1))) unsigned int*)g,
      (__attribute__((address_space(3))) unsigned int*)l, 16, 0, 0);
}

// ---------- elementwise convert x (fp32 -> bf16), 4 elems/thread ----------
__global__ void cvt_x_kernel(const float* __restrict__ x, u16* __restrict__ xb, int n4) {
  int i = blockIdx.x * 256 + threadIdx.x;
  if (i < n4) {
    float4 v = ((const float4*)x)[i];
    u32 lo = (u32)f2b(v.x) | ((u32)f2b(v.y) << 16);
    u32 hi = (u32)f2b(v.z) | ((u32)f2b(v.w) << 16);
    uint2 r; r.x = lo; r.y = hi;
    ((uint2*)xb)[i] = r;
  }
}

// ---------- concat bias ----------
__global__ void bias_cat_kernel(const float* __restrict__ bq, const float* __restrict__ bk,
                                const float* __restrict__ bv, float* __restrict__ bc) {
  int i = blockIdx.x * 256 + threadIdx.x;
  if (i < NQKV) bc[i] = (i < 2048) ? bq[i] : ((i < 2560) ? bk[i - 2048] : bv[i - 2560]);
}

// ---------- transpose + convert weights: src [2048(k) x srcCols(n)] fp32 -> dst[n][k] bf16 ----------
__global__ void transpose_cvt_kernel(const float* __restrict__ src, u16* __restrict__ dst,
                                     int srcCols, int dstRowOff) {
  __shared__ u16 t[64][65];
  int c0 = blockIdx.x * 64, r0 = blockIdx.y * 64;
  int tid = threadIdx.x;
  for (int i = tid; i < 4096; i += 256) {
    int r = i >> 6, c = i & 63;
    t[r][c] = f2b(src[(size_t)(r0 + r) * srcCols + c0 + c]);
  }
  __syncthreads();
  for (int i = tid; i < 4096; i += 256) {
    int n = i >> 6, k = i & 63;
    dst[(size_t)(dstRowOff + c0 + n) * 2048 + r0 + k] = t[k][n];
  }
}

// ---------- transpose V part of qkvb -> vt[b][kv][d][t] (bf16) ----------
__global__ void vt_transpose_kernel(const u16* __restrict__ qkvb, u16* __restrict__ vt) {
  __shared__ u16 t[64][65];
  int b  = blockIdx.z >> 2;
  int kv = blockIdx.z & 3;
  int d0 = blockIdx.y * 64;
  int t0 = blockIdx.x * 64;
  int tid = threadIdx.x;
  for (int i = tid; i < 4096; i += 256) {
    int r = i >> 6, c = i & 63;  // r = t-local, c = d-local
    t[r][c] = qkvb[(size_t)(b * TT + t0 + r) * NQKV + 2560 + kv * DH + d0 + c];
  }
  __syncthreads();
  for (int i = tid; i < 4096; i += 256) {
    int d = i >> 6, tl = i & 63;
    vt[((size_t)(b * NKV + kv) * DH + d0 + d) * TT + t0 + tl] = t[tl][d];
  }
}

// ---------- RoPE + pack kernel ----------
// qkvb [B*T][3072] bf16 (bias added). Writes qb[b][h][t][d], kb[b][kv][t][d] (bf16),
// and fp32 k,v outputs.
__global__ void rope_pack_kernel(const u16* __restrict__ qkvb, u16* __restrict__ qb,
                                 u16* __restrict__ kb, float* __restrict__ outK,
                                 float* __restrict__ outV) {
  __shared__ float sc_s[64], sc_c[64];
  int t = blockIdx.x, b = blockIdx.y;
  int tid = threadIdx.x;
  if (tid < 64) {
    // inv_freq = 1e6^(-i/64) = exp2(-i * log2(1e6)/64)
    float inv = exp2f(-(float)tid * 0.31143075889569023f);
    float th = (float)t * inv;
    sc_s[tid] = sinf(th);
    sc_c[tid] = cosf(th);
  }
  __syncthreads();
  const u16* row = qkvb + (size_t)(b * TT + t) * NQKV;
  // q: 16 heads x 64 pairs
  for (int i = tid; i < 1024; i += 256) {
    int h = i >> 6, d = i & 63;
    float x1 = b2f(row[h * DH + d]);
    float x2 = b2f(row[h * DH + d + 64]);
    float s = sc_s[d], c = sc_c[d];
    size_t base = ((size_t)(b * NH + h) * TT + t) * DH;
    qb[base + d]      = f2b(c * x1 - s * x2);
    qb[base + d + 64] = f2b(c * x2 + s * x1);
  }
  // k: 4 kv x 64 pairs
  for (int i = tid; i < 256; i += 256) {
    int kv = i >> 6, d = i & 63;
    float x1 = b2f(row[2048 + kv * DH + d]);
    float x2 = b2f(row[2048 + kv * DH + d + 64]);
    float s = sc_s[d], c = sc_c[d];
    float r1 = c * x1 - s * x2;
    float r2 = c * x2 + s * x1;
    size_t base = ((size_t)(b * NKV + kv) * TT + t) * DH;
    kb[base + d]      = f2b(r1);
    kb[base + d + 64] = f2b(r2);
    outK[base + d]      = r1;
    outK[base + d + 64] = r2;
  }
  // v: 512 elems straight copy
  for (int i = tid; i < 512; i += 256) {
    int kv = i >> 7, d = i & 127;
    outV[((size_t)(b * NKV + kv) * TT + t) * DH + d] = b2f(row[2560 + i]);
  }
}

// ---------- bf16 MFMA GEMM: C[M,N] = A[M,K] @ Bt[N,K]^T (+bias) ----------
// 128x128 tile, BK=32, 256 threads (2x2 waves, each 64x64 = 4x4 16x16x32 MFMAs)
template <int BIAS, int OUTF32>
__global__ __launch_bounds__(256, 3) void gemm_kernel(
    const u16* __restrict__ A, const u16* __restrict__ Bt,
    const float* __restrict__ bias, void* __restrict__ Cout,
    int M, int N, int K) {
  __shared__ u16 lA[128 * 32];
  __shared__ u16 lB[128 * 32];
  const int tid  = threadIdx.x;
  const int lane = tid & 63;
  const int wave = tid >> 6;
  const int quad = lane >> 4;
  const int l16  = lane & 15;
  const int m0 = blockIdx.y * 128;
  const int n0 = blockIdx.x * 128;
  const int wrow = (wave >> 1) * 64;
  const int wcol = (wave & 1) * 64;

  f32x4 acc[4][4];
  const f32x4 zero = {0.f, 0.f, 0.f, 0.f};
#pragma unroll
  for (int i = 0; i < 4; i++)
#pragma unroll
    for (int j = 0; j < 4; j++) acc[i][j] = zero;

  const int srow = tid >> 2;         // 0..63
  const int scol = (tid & 3) * 8;    // bf16 elems

  const u16* ga = A  + (size_t)(m0 + srow) * K + scol;
  const u16* gb = Bt + (size_t)(n0 + srow) * K + scol;

  for (int k0 = 0; k0 < K; k0 += 32) {
    gload16(ga + k0,                  &lA[tid * 8]);
    gload16(ga + k0 + (size_t)64 * K, &lA[2048 + tid * 8]);
    gload16(gb + k0,                  &lB[tid * 8]);
    gload16(gb + k0 + (size_t)64 * K, &lB[2048 + tid * 8]);
    __syncthreads();
    bf16x8 af[4], bf[4];
#pragma unroll
    for (int mi = 0; mi < 4; mi++)
      af[mi] = *(const bf16x8*)&lA[(wrow + mi * 16 + l16) * 32 + quad * 8];
#pragma unroll
    for (int ni = 0; ni < 4; ni++)
      bf[ni] = *(const bf16x8*)&lB[(wcol + ni * 16 + l16) * 32 + quad * 8];
#pragma unroll
    for (int mi = 0; mi < 4; mi++)
#pragma unroll
      for (int ni = 0; ni < 4; ni++)
        acc[mi][ni] = __builtin_amdgcn_mfma_f32_16x16x32_bf16(af[mi], bf[ni], acc[mi][ni], 0, 0, 0);
    __syncthreads();
  }

#pragma unroll
  for (int ni = 0; ni < 4; ni++) {
    int gcol = n0 + wcol + ni * 16 + l16;
    float bval = BIAS ? bias[gcol] : 0.0f;
#pragma unroll
    for (int mi = 0; mi < 4; mi++) {
#pragma unroll
      for (int r = 0; r < 4; r++) {
        int grow = m0 + wrow + mi * 16 + quad * 4 + r;
        float v = acc[mi][ni][r] + bval;
        if (OUTF32) ((float*)Cout)[(size_t)grow * N + gcol] = v;
        else        ((u16*)Cout)[(size_t)grow * N + gcol]   = f2b(v);
      }
    }
  }
}

// ---------- flash attention ----------
// grid: (32 qtiles, 32 b*h). 256 threads = 4 waves, each owns 16 q rows.
__global__ __launch_bounds__(256, 2) void attn_kernel(
    const u16* __restrict__ Q, const u16* __restrict__ Kb,
    const u16* __restrict__ Vt, u16* __restrict__ Ob) {
  __shared__ u16 lQ[64 * 128];
  __shared__ u16 lK[64 * 128];
  __shared__ u16 lV[128 * 64];
  __shared__ u16 lP[4 * 16 * 64];

  const int qt = (int)gridDim.x - 1 - (int)blockIdx.x;  // heavy tiles first
  const int bh = blockIdx.y;
  const int b = bh >> 4, h = bh & 15, kv = h >> 2;
  const u16* q  = Q  + (size_t)(b * NH + h) * TT * DH;
  const u16* kk = Kb + (size_t)(b * NKV + kv) * TT * DH;
  const u16* vt = Vt + (size_t)(b * NKV + kv) * DH * TT;

  const int tid = threadIdx.x;
  const int lane = tid & 63;
  const int wave = tid >> 6;
  const int quad = lane >> 4;
  const int l16 = lane & 15;
  const int q0 = qt * 64;

  // stage Q tile 64x128
  {
    int row = tid >> 4;
    int col = (tid & 15) * 8;
    const u16* g = q + (size_t)(q0 + row) * DH + col;
#pragma unroll
    for (int p = 0; p < 4; p++) gload16(g + (size_t)p * 16 * DH, &lQ[p * 2048 + tid * 8]);
  }

  float mrow[4], lrow[4];
#pragma unroll
  for (int r = 0; r < 4; r++) { mrow[r] = -__builtin_inff(); lrow[r] = 0.f; }
  f32x4 o[8];
  const f32x4 zero = {0.f, 0.f, 0.f, 0.f};
#pragma unroll
  for (int d = 0; d < 8; d++) o[d] = zero;

  for (int kt = 0; kt <= qt; ++kt) {
    const int kv0 = kt * 64;
    // stage K tile 64x128
    {
      int row = tid >> 4;
      int col = (tid & 15) * 8;
      const u16* g = kk + (size_t)(kv0 + row) * DH + col;
#pragma unroll
      for (int p = 0; p < 4; p++) gload16(g + (size_t)p * 16 * DH, &lK[p * 2048 + tid * 8]);
    }
    // stage Vt tile 128 x 64
    {
      int row = tid >> 3;
      int col = (tid & 7) * 8;
      const u16* g = vt + (size_t)row * TT + kv0 + col;
#pragma unroll
      for (int p = 0; p < 4; p++) gload16(g + (size_t)p * 32 * TT, &lV[p * 2048 + tid * 8]);
    }
    __syncthreads();

    // S = Q K^T : 16 rows x 64 cols per wave
    f32x4 s[4];
#pragma unroll
    for (int nt = 0; nt < 4; nt++) s[nt] = zero;
#pragma unroll
    for (int kc = 0; kc < 4; kc++) {
      bf16x8 aq = *(const bf16x8*)&lQ[(wave * 16 + l16) * 128 + kc * 32 + quad * 8];
#pragma unroll
      for (int nt = 0; nt < 4; nt++) {
        bf16x8 bk = *(const bf16x8*)&lK[(nt * 16 + l16) * 128 + kc * 32 + quad * 8];
        s[nt] = __builtin_amdgcn_mfma_f32_16x16x32_bf16(aq, bk, s[nt], 0, 0, 0);
      }
    }

    const float scale = 0.08838834764831845f;  // 1/sqrt(128)
    const bool diag = (kt == qt);
    float tmax[4];
#pragma unroll
    for (int r = 0; r < 4; r++) tmax[r] = -__builtin_inff();
#pragma unroll
    for (int nt = 0; nt < 4; nt++) {
      int colabs = kv0 + nt * 16 + l16;
#pragma unroll
      for (int r = 0; r < 4; r++) {
        float v = s[nt][r] * scale;
        if (diag) {
          int rowabs = q0 + wave * 16 + quad * 4 + r;
          if (colabs > rowabs) v = -__builtin_inff();
        }
        s[nt][r] = v;
        tmax[r] = fmaxf(tmax[r], v);
      }
    }
#pragma unroll
    for (int off = 8; off >= 1; off >>= 1)
#pragma unroll
      for (int r = 0; r < 4; r++) tmax[r] = fmaxf(tmax[r], __shfl_xor(tmax[r], off));

    float alpha[4], lsum[4];
#pragma unroll
    for (int r = 0; r < 4; r++) {
      float mn = fmaxf(mrow[r], tmax[r]);
      alpha[r] = __expf(mrow[r] - mn);
      mrow[r] = mn;
      lsum[r] = 0.f;
    }
#pragma unroll
    for (int nt = 0; nt < 4; nt++) {
#pragma unroll
      for (int r = 0; r < 4; r++) {
        float p = __expf(s[nt][r] - mrow[r]);
        lsum[r] += p;
        lP[wave * 1024 + (quad * 4 + r) * 64 + nt * 16 + l16] = f2b(p);
      }
    }
#pragma unroll
    for (int off = 8; off >= 1; off >>= 1)
#pragma unroll
      for (int r = 0; r < 4; r++) lsum[r] += __shfl_xor(lsum[r], off);
#pragma unroll
    for (int r = 0; r < 4; r++) lrow[r] = lrow[r] * alpha[r] + lsum[r];
#pragma unroll
    for (int d = 0; d < 8; d++)
#pragma unroll
      for (int r = 0; r < 4; r++) o[d][r] *= alpha[r];

    // PV: P[16x64] @ V[64x128]
#pragma unroll
    for (int ks = 0; ks < 2; ks++) {
      bf16x8 ap = *(const bf16x8*)&lP[wave * 1024 + l16 * 64 + ks * 32 + quad * 8];
#pragma unroll
      for (int dt = 0; dt < 8; dt++) {
        bf16x8 bv = *(const bf16x8*)&lV[(dt * 16 + l16) * 64 + ks * 32 + quad * 8];
        o[dt] = __builtin_amdgcn_mfma_f32_16x16x32_bf16(ap, bv, o[dt], 0, 0, 0);
      }
    }
    __syncthreads();
  }

  // epilogue: Ob[b*T + t][h*128 + d] bf16
  float inv[4];
#pragma unroll
  for (int r = 0; r < 4; r++) inv[r] = 1.0f / lrow[r];
#pragma unroll
  for (int dt = 0; dt < 8; dt++) {
#pragma unroll
    for (int r = 0; r < 4; r++) {
      int t = q0 + wave * 16 + quad * 4 + r;
      Ob[(size_t)(b * TT + t) * DMODEL + h * DH + dt * 16 + l16] = f2b(o[dt][r] * inv[r]);
    }
  }
}

// ---------- launcher ----------
extern "C" void kernel_launch(void* const* d_in, const int* in_sizes, int n_in,
                              void* d_out, int out_size, void* d_ws, size_t ws_size,
                              hipStream_t stream) {
  (void)in_sizes; (void)n_in; (void)out_size; (void)ws_size;
  const float* x  = (const float*)d_in[0];
  const float* wq = (const float*)d_in[1];
  const float* bq = (const float*)d_in[2];
  const float* wk = (const float*)d_in[3];
  const float* bk = (const float*)d_in[4];
  const float* wv = (const float*)d_in[5];
  const float* bv = (const float*)d_in[6];
  const float* wo = (const float*)d_in[7];
  float* out = (float*)d_out;

  char* ws = (char*)d_ws;
  u16*   xb    = (u16*)(ws);                       // 16,777,216 B
  u16*   wqkvT = (u16*)(ws + 16777216);            // 12,582,912
  u16*   woT   = (u16*)(ws + 29360128);            //  8,388,608
  float* bcat  = (float*)(ws + 37748736);          //     12,288
  u16*   qkvb  = (u16*)(ws + 37761024);            // 25,165,824
  u16*   qb    = (u16*)(ws + 62926848);            // 16,777,216
  u16*   kb    = (u16*)(ws + 79704064);            //  4,194,304
  u16*   vt    = (u16*)(ws + 83898368);            //  4,194,304
  u16*   ob    = (u16*)(ws + 88092672);            // 16,777,216  (total ~104.9 MB)

  float* outK = out + (size_t)BB * TT * DMODEL;            // 8,388,608
  float* outV = outK + (size_t)BB * NKV * TT * DH;         // +2,097,152

  cvt_x_kernel<<<8192, 256, 0, stream>>>(x, xb, (BB * TT * DMODEL) / 4);
  bias_cat_kernel<<<12, 256, 0, stream>>>(bq, bk, bv, bcat);
  transpose_cvt_kernel<<<dim3(32, 32), 256, 0, stream>>>(wq, wqkvT, 2048, 0);
  transpose_cvt_kernel<<<dim3(8, 32),  256, 0, stream>>>(wk, wqkvT, 512, 2048);
  transpose_cvt_kernel<<<dim3(8, 32),  256, 0, stream>>>(wv, wqkvT, 512, 2560);
  transpose_cvt_kernel<<<dim3(32, 32), 256, 0, stream>>>(wo, woT, 2048, 0);

  gemm_kernel<1, 0><<<dim3(NQKV / 128, MM / 128), 256, 0, stream>>>(
      xb, wqkvT, bcat, qkvb, MM, NQKV, DMODEL);

  rope_pack_kernel<<<dim3(TT, BB), 256, 0, stream>>>(qkvb, qb, kb, outK, outV);
  vt_transpose_kernel<<<dim3(TT / 64, DH / 64, BB * NKV), 256, 0, stream>>>(qkvb, vt);

  attn_kernel<<<dim3(TT / 64, BB * NH), 256, 0, stream>>>(qb, kb, vt, ob);

  gemm_kernel<0, 1><<<dim3(DMODEL / 128, MM / 128), 256, 0, stream>>>(
      ob, woT, nullptr, out, MM, DMODEL, DMODEL);
}

// Round 2
// 415.291 us; speedup vs baseline: 1.3932x; 1.3932x over previous
//
#include <hip/hip_runtime.h>
#include <hip/hip_bf16.h>
#include <math.h>

// ---------- constants ----------
#define BB 2
#define TT 2048
#define DMODEL 2048
#define NH 16
#define NKV 4
#define DH 128
#define NQKV 3072            // 2048 + 512 + 512
#define MM (BB*TT)           // 4096

typedef unsigned short u16;
typedef unsigned int u32;

typedef __bf16 bf16x8 __attribute__((ext_vector_type(8)));
typedef float f32x4 __attribute__((ext_vector_type(4)));

__device__ __forceinline__ u16 f2b(float f) {
  union { float f; u32 u; } v; v.f = f;
  u32 r = v.u + 0x7fffu + ((v.u >> 16) & 1u);
  return (u16)(r >> 16);
}
__device__ __forceinline__ float b2f(u16 h) {
  union { u32 u; float f; } v; v.u = ((u32)h) << 16;
  return v.f;
}

// async global->LDS, 16B per lane
__device__ __forceinline__ void gload16(const void* g, void* l) {
  __builtin_amdgcn_global_load_lds(
      (const __attribute__((address_space(1))) unsigned int*)g,
      (__attribute__((address_space(3))) unsigned int*)l, 16, 0, 0);
}

// ---------- elementwise convert x (fp32 -> bf16), 4 elems/thread ----------
__global__ void cvt_x_kernel(const float* __restrict__ x, u16* __restrict__ xb, int n4) {
  int i = blockIdx.x * 256 + threadIdx.x;
  if (i < n4) {
    float4 v = ((const float4*)x)[i];
    u32 lo = (u32)f2b(v.x) | ((u32)f2b(v.y) << 16);
    u32 hi = (u32)f2b(v.z) | ((u32)f2b(v.w) << 16);
    uint2 r; r.x = lo; r.y = hi;
    ((uint2*)xb)[i] = r;
  }
}

// ---------- concat bias ----------
__global__ void bias_cat_kernel(const float* __restrict__ bq, const float* __restrict__ bk,
                                const float* __restrict__ bv, float* __restrict__ bc) {
  int i = blockIdx.x * 256 + threadIdx.x;
  if (i < NQKV) bc[i] = (i < 2048) ? bq[i] : ((i < 2560) ? bk[i - 2048] : bv[i - 2560]);
}

// ---------- transpose + convert weights: src [2048(k) x srcCols(n)] fp32 -> dst[n][k] bf16 ----------
__global__ void transpose_cvt_kernel(const float* __restrict__ src, u16* __restrict__ dst,
                                     int srcCols, int dstRowOff) {
  __shared__ u16 t[64][65];
  int c0 = blockIdx.x * 64, r0 = blockIdx.y * 64;
  int tid = threadIdx.x;
  for (int i = tid; i < 4096; i += 256) {
    int r = i >> 6, c = i & 63;
    t[r][c] = f2b(src[(size_t)(r0 + r) * srcCols + c0 + c]);
  }
  __syncthreads();
  for (int i = tid; i < 4096; i += 256) {
    int n = i >> 6, k = i & 63;
    dst[(size_t)(dstRowOff + c0 + n) * 2048 + r0 + k] = t[k][n];
  }
}

// ---------- transpose V part of qkvb -> vt tiled [b][kv][ttile32][kc8][d128][8] ----------
__global__ void vt_transpose_kernel(const u16* __restrict__ qkvb, u16* __restrict__ vt) {
  __shared__ u16 t[64][65];
  int bkv = blockIdx.z;                  // b*4+kv
  int b  = bkv >> 2;
  int kv = bkv & 3;
  int d0 = blockIdx.y * 64;
  int t0 = blockIdx.x * 64;
  int tid = threadIdx.x;
  for (int i = tid; i < 4096; i += 256) {
    int r = i >> 6, c = i & 63;  // r = t-local, c = d-local
    t[r][c] = qkvb[(size_t)(b * TT + t0 + r) * NQKV + 2560 + kv * DH + d0 + c];
  }
  __syncthreads();
  size_t tilebase = ((size_t)bkv * 32 + (t0 >> 6)) * 8192;
  for (int i = tid; i < 512; i += 256) {
    int dl = i & 63, kc = i >> 6;        // kc in 0..7 (t-chunk)
    u16 tmp[8];
#pragma unroll
    for (int j = 0; j < 8; j++) tmp[j] = t[kc * 8 + j][dl];
    *(uint4*)&vt[tilebase + (size_t)(kc * 128 + d0 + dl) * 8] = *(const uint4*)tmp;
  }
}

// ---------- RoPE + pack kernel ----------
// qkvb [B*T][3072] bf16 (bias added). Writes qb tiled [b][h][ttile32][kc16][row64][8],
// kb tiled [b][kv][ttile32][kc16][row64][8], and fp32 k,v outputs (row-major).
__global__ void rope_pack_kernel(const u16* __restrict__ qkvb, u16* __restrict__ qb,
                                 u16* __restrict__ kb, float* __restrict__ outK,
                                 float* __restrict__ outV) {
  __shared__ float sc_s[64], sc_c[64];
  int t = blockIdx.x, b = blockIdx.y;
  int tid = threadIdx.x;
  if (tid < 64) {
    float inv = exp2f(-(float)tid * 0.31143075889569023f);
    float th = (float)t * inv;
    sc_s[tid] = sinf(th);
    sc_c[tid] = cosf(th);
  }
  __syncthreads();
  const u16* row = qkvb + (size_t)(b * TT + t) * NQKV;
  const int rl = t & 63;        // row-local in 64-tile
  const int tt = t >> 6;        // tile index
  // q: 16 heads x 64 pairs
  for (int i = tid; i < 1024; i += 256) {
    int h = i >> 6, d = i & 63;
    float x1 = b2f(row[h * DH + d]);
    float x2 = b2f(row[h * DH + d + 64]);
    float s = sc_s[d], c = sc_c[d];
    size_t tb = ((size_t)(b * NH + h) * 32 + tt) * 8192;
    int kc = d >> 3, e = d & 7;
    qb[tb + (size_t)((kc)     * 64 + rl) * 8 + e] = f2b(c * x1 - s * x2);
    qb[tb + (size_t)((kc + 8) * 64 + rl) * 8 + e] = f2b(c * x2 + s * x1);
  }
  // k: 4 kv x 64 pairs
  {
    int kv = tid >> 6, d = tid & 63;
    float x1 = b2f(row[2048 + kv * DH + d]);
    float x2 = b2f(row[2048 + kv * DH + d + 64]);
    float s = sc_s[d], c = sc_c[d];
    float r1 = c * x1 - s * x2;
    float r2 = c * x2 + s * x1;
    size_t tb = ((size_t)(b * NKV + kv) * 32 + tt) * 8192;
    int kc = d >> 3, e = d & 7;
    kb[tb + (size_t)((kc)     * 64 + rl) * 8 + e] = f2b(r1);
    kb[tb + (size_t)((kc + 8) * 64 + rl) * 8 + e] = f2b(r2);
    size_t base = ((size_t)(b * NKV + kv) * TT + t) * DH;
    outK[base + d]      = r1;
    outK[base + d + 64] = r2;
  }
  // v: 512 elems straight copy
  for (int i = tid; i < 512; i += 256) {
    int kv = i >> 7, d = i & 127;
    outV[((size_t)(b * NKV + kv) * TT + t) * DH + d] = b2f(row[2560 + i]);
  }
}

// ---------- bf16 MFMA GEMM: C[M,N] = A[M,K] @ Bt[N,K]^T (+bias) ----------
template <int BIAS, int OUTF32>
__global__ __launch_bounds__(256, 3) void gemm_kernel(
    const u16* __restrict__ A, const u16* __restrict__ Bt,
    const float* __restrict__ bias, void* __restrict__ Cout,
    int M, int N, int K) {
  __shared__ u16 lA[128 * 32];
  __shared__ u16 lB[128 * 32];
  const int tid  = threadIdx.x;
  const int lane = tid & 63;
  const int wave = tid >> 6;
  const int quad = lane >> 4;
  const int l16  = lane & 15;
  const int m0 = blockIdx.y * 128;
  const int n0 = blockIdx.x * 128;
  const int wrow = (wave >> 1) * 64;
  const int wcol = (wave & 1) * 64;

  f32x4 acc[4][4];
  const f32x4 zero = {0.f, 0.f, 0.f, 0.f};
#pragma unroll
  for (int i = 0; i < 4; i++)
#pragma unroll
    for (int j = 0; j < 4; j++) acc[i][j] = zero;

  const int srow = tid >> 2;
  const int scol = (tid & 3) * 8;

  const u16* ga = A  + (size_t)(m0 + srow) * K + scol;
  const u16* gb = Bt + (size_t)(n0 + srow) * K + scol;

  for (int k0 = 0; k0 < K; k0 += 32) {
    gload16(ga + k0,                  &lA[tid * 8]);
    gload16(ga + k0 + (size_t)64 * K, &lA[2048 + tid * 8]);
    gload16(gb + k0,                  &lB[tid * 8]);
    gload16(gb + k0 + (size_t)64 * K, &lB[2048 + tid * 8]);
    __syncthreads();
    bf16x8 af[4], bf[4];
#pragma unroll
    for (int mi = 0; mi < 4; mi++)
      af[mi] = *(const bf16x8*)&lA[(wrow + mi * 16 + l16) * 32 + quad * 8];
#pragma unroll
    for (int ni = 0; ni < 4; ni++)
      bf[ni] = *(const bf16x8*)&lB[(wcol + ni * 16 + l16) * 32 + quad * 8];
#pragma unroll
    for (int mi = 0; mi < 4; mi++)
#pragma unroll
      for (int ni = 0; ni < 4; ni++)
        acc[mi][ni] = __builtin_amdgcn_mfma_f32_16x16x32_bf16(af[mi], bf[ni], acc[mi][ni], 0, 0, 0);
    __syncthreads();
  }

#pragma unroll
  for (int ni = 0; ni < 4; ni++) {
    int gcol = n0 + wcol + ni * 16 + l16;
    float bval = BIAS ? bias[gcol] : 0.0f;
#pragma unroll
    for (int mi = 0; mi < 4; mi++) {
#pragma unroll
      for (int r = 0; r < 4; r++) {
        int grow = m0 + wrow + mi * 16 + quad * 4 + r;
        float v = acc[mi][ni][r] + bval;
        if (OUTF32) ((float*)Cout)[(size_t)grow * N + gcol] = v;
        else        ((u16*)Cout)[(size_t)grow * N + gcol]   = f2b(v);
      }
    }
  }
}

// ---------- flash attention v2 ----------
// Tiled global layouts: Q/K [tile][kc16][row64][8], Vt [tile][kc8][d128][8].
// All LDS fragment reads lane-contiguous (conflict-free). Q frags in registers.
// grid: (32 qtiles, 32 b*h). 256 threads = 4 waves, each owns 16 q rows.
__global__ __launch_bounds__(256, 3) void attn_kernel(
    const u16* __restrict__ Qt, const u16* __restrict__ Kt,
    const u16* __restrict__ Vt, u16* __restrict__ Ob) {
  __shared__ u16 sm[20480];   // kbuf 8192 | vbuf 8192 | pbuf 4096  (40 KB)
  u16* kbuf = sm;
  u16* vbuf = sm + 8192;
  u16* pbuf = sm + 16384;

  const int qt = (int)gridDim.x - 1 - (int)blockIdx.x;  // heavy tiles first
  const int bh = blockIdx.y;
  const int b = bh >> 4, h = bh & 15, kv = h >> 2;
  const int tid = threadIdx.x;
  const int lane = tid & 63;
  const int wave = tid >> 6;
  const int quad = lane >> 4;
  const int l16 = lane & 15;
  const int q0 = qt * 64;

  const u16* qtile = Qt + ((size_t)(b * NH + h) * 32 + qt) * 8192;
  const u16* kbase = Kt + (size_t)(b * NKV + kv) * 32 * 8192;
  const u16* vbase = Vt + (size_t)(b * NKV + kv) * 32 * 8192;

  // stage Q tile (16KB) into kbuf, pull fragments to registers
#pragma unroll
  for (int p = 0; p < 4; p++) gload16(qtile + p * 2048 + tid * 8, &kbuf[p * 2048 + tid * 8]);
  __syncthreads();
  bf16x8 af[4];
#pragma unroll
  for (int kc = 0; kc < 4; kc++)
    af[kc] = *(const bf16x8*)&kbuf[(size_t)((kc * 4 + quad) * 64 + wave * 16 + l16) * 8];
  __syncthreads();

  float mrow[4], lrow[4];
#pragma unroll
  for (int r = 0; r < 4; r++) { mrow[r] = -__builtin_inff(); lrow[r] = 0.f; }
  f32x4 o[8];
  const f32x4 zero = {0.f, 0.f, 0.f, 0.f};
#pragma unroll
  for (int d = 0; d < 8; d++) o[d] = zero;

  const int myrow = wave * 16 + quad * 4;   // + r = row-local; + q0 = absolute

  for (int kt = 0; kt <= qt; ++kt) {
    const u16* ksrc = kbase + (size_t)kt * 8192;
    const u16* vsrc = vbase + (size_t)kt * 8192;
#pragma unroll
    for (int p = 0; p < 4; p++) {
      gload16(ksrc + p * 2048 + tid * 8, &kbuf[p * 2048 + tid * 8]);
      gload16(vsrc + p * 2048 + tid * 8, &vbuf[p * 2048 + tid * 8]);
    }
    __syncthreads();

    // S = Q K^T : 16 rows x 64 cols per wave
    f32x4 s[4];
#pragma unroll
    for (int nt = 0; nt < 4; nt++) s[nt] = zero;
#pragma unroll
    for (int kc = 0; kc < 4; kc++) {
#pragma unroll
      for (int nt = 0; nt < 4; nt++) {
        bf16x8 bk = *(const bf16x8*)&kbuf[(size_t)((kc * 4 + quad) * 64 + nt * 16 + l16) * 8];
        s[nt] = __builtin_amdgcn_mfma_f32_16x16x32_bf16(af[kc], bk, s[nt], 0, 0, 0);
      }
    }

    const float scale = 0.08838834764831845f;  // 1/sqrt(128)
    float tmax[4];
#pragma unroll
    for (int r = 0; r < 4; r++) tmax[r] = -__builtin_inff();
    if (kt == qt) {
#pragma unroll
      for (int nt = 0; nt < 4; nt++) {
        int colabs = nt * 16 + l16;           // relative to tile; rows also relative
#pragma unroll
        for (int r = 0; r < 4; r++) {
          float v = s[nt][r] * scale;
          if (colabs > myrow + r) v = -__builtin_inff();
          s[nt][r] = v;
          tmax[r] = fmaxf(tmax[r], v);
        }
      }
    } else {
#pragma unroll
      for (int nt = 0; nt < 4; nt++)
#pragma unroll
        for (int r = 0; r < 4; r++) {
          float v = s[nt][r] * scale;
          s[nt][r] = v;
          tmax[r] = fmaxf(tmax[r], v);
        }
    }
#pragma unroll
    for (int off = 8; off >= 1; off >>= 1)
#pragma unroll
      for (int r = 0; r < 4; r++) tmax[r] = fmaxf(tmax[r], __shfl_xor(tmax[r], off));

    float alpha[4], lsum[4];
#pragma unroll
    for (int r = 0; r < 4; r++) {
      float mn = fmaxf(mrow[r], tmax[r]);
      alpha[r] = __expf(mrow[r] - mn);
      mrow[r] = mn;
      lsum[r] = 0.f;
    }
    // write P in tiled A-frag layout [kcP 8][row 16][8] per wave
#pragma unroll
    for (int nt = 0; nt < 4; nt++) {
      int kcP = nt * 2 + (l16 >> 3);
#pragma unroll
      for (int r = 0; r < 4; r++) {
        float p = __expf(s[nt][r] - mrow[r]);
        lsum[r] += p;
        pbuf[wave * 1024 + (kcP * 16 + quad * 4 + r) * 8 + (l16 & 7)] = f2b(p);
      }
    }
#pragma unroll
    for (int off = 8; off >= 1; off >>= 1)
#pragma unroll
      for (int r = 0; r < 4; r++) lsum[r] += __shfl_xor(lsum[r], off);
#pragma unroll
    for (int r = 0; r < 4; r++) lrow[r] = lrow[r] * alpha[r] + lsum[r];
#pragma unroll
    for (int d = 0; d < 8; d++)
#pragma unroll
      for (int r = 0; r < 4; r++) o[d][r] *= alpha[r];

    // PV: P[16x64] @ V[64x128]
#pragma unroll
    for (int ks = 0; ks < 2; ks++) {
      bf16x8 ap = *(const bf16x8*)&pbuf[(size_t)(wave * 1024 + ((ks * 4 + quad) * 16 + l16) * 8)];
#pragma unroll
      for (int dt = 0; dt < 8; dt++) {
        bf16x8 bv = *(const bf16x8*)&vbuf[(size_t)((ks * 4 + quad) * 128 + dt * 16 + l16) * 8];
        o[dt] = __builtin_amdgcn_mfma_f32_16x16x32_bf16(ap, bv, o[dt], 0, 0, 0);
      }
    }
    __syncthreads();
  }

  // epilogue: Ob[b*T + t][h*128 + d] bf16 (row-major, feeds out-GEMM)
  float inv[4];
#pragma unroll
  for (int r = 0; r < 4; r++) inv[r] = 1.0f / lrow[r];
#pragma unroll
  for (int dt = 0; dt < 8; dt++) {
#pragma unroll
    for (int r = 0; r < 4; r++) {
      int t = q0 + myrow + r;
      Ob[(size_t)(b * TT + t) * DMODEL + h * DH + dt * 16 + l16] = f2b(o[dt][r] * inv[r]);
    }
  }
}

// ---------- launcher ----------
extern "C" void kernel_launch(void* const* d_in, const int* in_sizes, int n_in,
                              void* d_out, int out_size, void* d_ws, size_t ws_size,
                              hipStream_t stream) {
  (void)in_sizes; (void)n_in; (void)out_size; (void)ws_size;
  const float* x  = (const float*)d_in[0];
  const float* wq = (const float*)d_in[1];
  const float* bq = (const float*)d_in[2];
  const float* wk = (const float*)d_in[3];
  const float* bk = (const float*)d_in[4];
  const float* wv = (const float*)d_in[5];
  const float* bv = (const float*)d_in[6];
  const float* wo = (const float*)d_in[7];
  float* out = (float*)d_out;

  char* ws = (char*)d_ws;
  u16*   xb    = (u16*)(ws);                       // 16,777,216 B
  u16*   wqkvT = (u16*)(ws + 16777216);            // 12,582,912
  u16*   woT   = (u16*)(ws + 29360128);            //  8,388,608
  float* bcat  = (float*)(ws + 37748736);          //     12,288
  u16*   qkvb  = (u16*)(ws + 37761024);            // 25,165,824
  u16*   qb    = (u16*)(ws + 62926848);            // 16,777,216 (tiled)
  u16*   kb    = (u16*)(ws + 79704064);            //  4,194,304 (tiled)
  u16*   vt    = (u16*)(ws + 83898368);            //  4,194,304 (tiled)
  u16*   ob    = (u16*)(ws + 88092672);            // 16,777,216

  float* outK = out + (size_t)BB * TT * DMODEL;
  float* outV = outK + (size_t)BB * NKV * TT * DH;

  cvt_x_kernel<<<8192, 256, 0, stream>>>(x, xb, (BB * TT * DMODEL) / 4);
  bias_cat_kernel<<<12, 256, 0, stream>>>(bq, bk, bv, bcat);
  transpose_cvt_kernel<<<dim3(32, 32), 256, 0, stream>>>(wq, wqkvT, 2048, 0);
  transpose_cvt_kernel<<<dim3(8, 32),  256, 0, stream>>>(wk, wqkvT, 512, 2048);
  transpose_cvt_kernel<<<dim3(8, 32),  256, 0, stream>>>(wv, wqkvT, 512, 2560);
  transpose_cvt_kernel<<<dim3(32, 32), 256, 0, stream>>>(wo, woT, 2048, 0);

  gemm_kernel<1, 0><<<dim3(NQKV / 128, MM / 128), 256, 0, stream>>>(
      xb, wqkvT, bcat, qkvb, MM, NQKV, DMODEL);

  rope_pack_kernel<<<dim3(TT, BB), 256, 0, stream>>>(qkvb, qb, kb, outK, outV);
  vt_transpose_kernel<<<dim3(TT / 64, DH / 64, BB * NKV), 256, 0, stream>>>(qkvb, vt);

  attn_kernel<<<dim3(TT / 64, BB * NH), 256, 0, stream>>>(qb, kb, vt, ob);

  gemm_kernel<0, 1><<<dim3(DMODEL / 128, MM / 128), 256, 0, stream>>>(
      ob, woT, nullptr, out, MM, DMODEL, DMODEL);
}

// Round 3
// 349.884 us; speedup vs baseline: 1.6536x; 1.1869x over previous
//
#include <hip/hip_runtime.h>
#include <hip/hip_bf16.h>
#include <math.h>

// ---------- constants ----------
#define BB 2
#define TT 2048
#define DMODEL 2048
#define NH 16
#define NKV 4
#define DH 128
#define NQKV 3072            // 2048 + 512 + 512
#define MM (BB*TT)           // 4096

typedef unsigned short u16;
typedef unsigned int u32;

typedef __bf16 bf16x8 __attribute__((ext_vector_type(8)));
typedef float f32x4 __attribute__((ext_vector_type(4)));

__device__ __forceinline__ u16 f2b(float f) {
  union { float f; u32 u; } v; v.f = f;
  u32 r = v.u + 0x7fffu + ((v.u >> 16) & 1u);
  return (u16)(r >> 16);
}
__device__ __forceinline__ float b2f(u16 h) {
  union { u32 u; float f; } v; v.u = ((u32)h) << 16;
  return v.f;
}

// async global->LDS, 16B per lane
__device__ __forceinline__ void gload16(const void* g, void* l) {
  __builtin_amdgcn_global_load_lds(
      (const __attribute__((address_space(1))) unsigned int*)g,
      (__attribute__((address_space(3))) unsigned int*)l, 16, 0, 0);
}

// DPP cross-lane (16-lane row) reduction helpers
template <int CTRL>
__device__ __forceinline__ float dpp_f(float x) {
  union { float f; int i; } a, o;
  a.f = x;
  o.i = __builtin_amdgcn_update_dpp(0, a.i, CTRL, 0xF, 0xF, false);
  return o.f;
}
__device__ __forceinline__ float red16_max(float x) {
  x = fmaxf(x, dpp_f<0xB1>(x));   // quad_perm [1,0,3,2]  (xor 1)
  x = fmaxf(x, dpp_f<0x4E>(x));   // quad_perm [2,3,0,1]  (xor 2)
  x = fmaxf(x, dpp_f<0x124>(x));  // row_ror:4
  x = fmaxf(x, dpp_f<0x128>(x));  // row_ror:8
  return x;
}
__device__ __forceinline__ float red16_sum(float x) {
  x += dpp_f<0xB1>(x);
  x += dpp_f<0x4E>(x);
  x += dpp_f<0x124>(x);
  x += dpp_f<0x128>(x);
  return x;
}
__device__ __forceinline__ float fast_exp2(float x) {
#if __has_builtin(__builtin_amdgcn_exp2f)
  return __builtin_amdgcn_exp2f(x);
#else
  return __expf(x * 0.6931471805599453f);
#endif
}

// ---------- elementwise convert x (fp32 -> bf16), 4 elems/thread ----------
__global__ void cvt_x_kernel(const float* __restrict__ x, u16* __restrict__ xb, int n4) {
  int i = blockIdx.x * 256 + threadIdx.x;
  if (i < n4) {
    float4 v = ((const float4*)x)[i];
    u32 lo = (u32)f2b(v.x) | ((u32)f2b(v.y) << 16);
    u32 hi = (u32)f2b(v.z) | ((u32)f2b(v.w) << 16);
    uint2 r; r.x = lo; r.y = hi;
    ((uint2*)xb)[i] = r;
  }
}

// ---------- concat bias ----------
__global__ void bias_cat_kernel(const float* __restrict__ bq, const float* __restrict__ bk,
                                const float* __restrict__ bv, float* __restrict__ bc) {
  int i = blockIdx.x * 256 + threadIdx.x;
  if (i < NQKV) bc[i] = (i < 2048) ? bq[i] : ((i < 2560) ? bk[i - 2048] : bv[i - 2560]);
}

// ---------- transpose + convert weights: src [2048(k) x srcCols(n)] fp32 -> dst[n][k] bf16 ----------
__global__ void transpose_cvt_kernel(const float* __restrict__ src, u16* __restrict__ dst,
                                     int srcCols, int dstRowOff) {
  __shared__ u16 t[64][65];
  int c0 = blockIdx.x * 64, r0 = blockIdx.y * 64;
  int tid = threadIdx.x;
  for (int i = tid; i < 4096; i += 256) {
    int r = i >> 6, c = i & 63;
    t[r][c] = f2b(src[(size_t)(r0 + r) * srcCols + c0 + c]);
  }
  __syncthreads();
  for (int i = tid; i < 4096; i += 256) {
    int n = i >> 6, k = i & 63;
    dst[(size_t)(dstRowOff + c0 + n) * 2048 + r0 + k] = t[k][n];
  }
}

// ---------- transpose V part of qkvb -> vt tiled [b][kv][ttile32][kc8][d128][8] ----------
__global__ void vt_transpose_kernel(const u16* __restrict__ qkvb, u16* __restrict__ vt) {
  __shared__ u16 t[64][65];
  int bkv = blockIdx.z;                  // b*4+kv
  int b  = bkv >> 2;
  int kv = bkv & 3;
  int d0 = blockIdx.y * 64;
  int t0 = blockIdx.x * 64;
  int tid = threadIdx.x;
  for (int i = tid; i < 4096; i += 256) {
    int r = i >> 6, c = i & 63;  // r = t-local, c = d-local
    t[r][c] = qkvb[(size_t)(b * TT + t0 + r) * NQKV + 2560 + kv * DH + d0 + c];
  }
  __syncthreads();
  size_t tilebase = ((size_t)bkv * 32 + (t0 >> 6)) * 8192;
  for (int i = tid; i < 512; i += 256) {
    int dl = i & 63, kc = i >> 6;        // kc in 0..7 (t-chunk)
    u16 tmp[8];
#pragma unroll
    for (int j = 0; j < 8; j++) tmp[j] = t[kc * 8 + j][dl];
    *(uint4*)&vt[tilebase + (size_t)(kc * 128 + d0 + dl) * 8] = *(const uint4*)tmp;
  }
}

// ---------- RoPE + pack kernel ----------
__global__ void rope_pack_kernel(const u16* __restrict__ qkvb, u16* __restrict__ qb,
                                 u16* __restrict__ kb, float* __restrict__ outK,
                                 float* __restrict__ outV) {
  __shared__ float sc_s[64], sc_c[64];
  int t = blockIdx.x, b = blockIdx.y;
  int tid = threadIdx.x;
  if (tid < 64) {
    float inv = exp2f(-(float)tid * 0.31143075889569023f);
    float th = (float)t * inv;
    sc_s[tid] = sinf(th);
    sc_c[tid] = cosf(th);
  }
  __syncthreads();
  const u16* row = qkvb + (size_t)(b * TT + t) * NQKV;
  const int rl = t & 63;        // row-local in 64-tile
  const int tt = t >> 6;        // tile index
  for (int i = tid; i < 1024; i += 256) {
    int h = i >> 6, d = i & 63;
    float x1 = b2f(row[h * DH + d]);
    float x2 = b2f(row[h * DH + d + 64]);
    float s = sc_s[d], c = sc_c[d];
    size_t tb = ((size_t)(b * NH + h) * 32 + tt) * 8192;
    int kc = d >> 3, e = d & 7;
    qb[tb + (size_t)((kc)     * 64 + rl) * 8 + e] = f2b(c * x1 - s * x2);
    qb[tb + (size_t)((kc + 8) * 64 + rl) * 8 + e] = f2b(c * x2 + s * x1);
  }
  {
    int kv = tid >> 6, d = tid & 63;
    float x1 = b2f(row[2048 + kv * DH + d]);
    float x2 = b2f(row[2048 + kv * DH + d + 64]);
    float s = sc_s[d], c = sc_c[d];
    float r1 = c * x1 - s * x2;
    float r2 = c * x2 + s * x1;
    size_t tb = ((size_t)(b * NKV + kv) * 32 + tt) * 8192;
    int kc = d >> 3, e = d & 7;
    kb[tb + (size_t)((kc)     * 64 + rl) * 8 + e] = f2b(r1);
    kb[tb + (size_t)((kc + 8) * 64 + rl) * 8 + e] = f2b(r2);
    size_t base = ((size_t)(b * NKV + kv) * TT + t) * DH;
    outK[base + d]      = r1;
    outK[base + d + 64] = r2;
  }
  for (int i = tid; i < 512; i += 256) {
    int kv = i >> 7, d = i & 127;
    outV[((size_t)(b * NKV + kv) * TT + t) * DH + d] = b2f(row[2560 + i]);
  }
}

// ---------- bf16 MFMA GEMM: C[M,N] = A[M,K] @ Bt[N,K]^T (+bias) ----------
template <int BIAS, int OUTF32>
__global__ __launch_bounds__(256, 3) void gemm_kernel(
    const u16* __restrict__ A, const u16* __restrict__ Bt,
    const float* __restrict__ bias, void* __restrict__ Cout,
    int M, int N, int K) {
  __shared__ u16 lA[128 * 32];
  __shared__ u16 lB[128 * 32];
  const int tid  = threadIdx.x;
  const int lane = tid & 63;
  const int wave = tid >> 6;
  const int quad = lane >> 4;
  const int l16  = lane & 15;
  const int m0 = blockIdx.y * 128;
  const int n0 = blockIdx.x * 128;
  const int wrow = (wave >> 1) * 64;
  const int wcol = (wave & 1) * 64;

  f32x4 acc[4][4];
  const f32x4 zero = {0.f, 0.f, 0.f, 0.f};
#pragma unroll
  for (int i = 0; i < 4; i++)
#pragma unroll
    for (int j = 0; j < 4; j++) acc[i][j] = zero;

  const int srow = tid >> 2;
  const int scol = (tid & 3) * 8;

  const u16* ga = A  + (size_t)(m0 + srow) * K + scol;
  const u16* gb = Bt + (size_t)(n0 + srow) * K + scol;

  for (int k0 = 0; k0 < K; k0 += 32) {
    gload16(ga + k0,                  &lA[tid * 8]);
    gload16(ga + k0 + (size_t)64 * K, &lA[2048 + tid * 8]);
    gload16(gb + k0,                  &lB[tid * 8]);
    gload16(gb + k0 + (size_t)64 * K, &lB[2048 + tid * 8]);
    __syncthreads();
    bf16x8 af[4], bf[4];
#pragma unroll
    for (int mi = 0; mi < 4; mi++)
      af[mi] = *(const bf16x8*)&lA[(wrow + mi * 16 + l16) * 32 + quad * 8];
#pragma unroll
    for (int ni = 0; ni < 4; ni++)
      bf[ni] = *(const bf16x8*)&lB[(wcol + ni * 16 + l16) * 32 + quad * 8];
#pragma unroll
    for (int mi = 0; mi < 4; mi++)
#pragma unroll
      for (int ni = 0; ni < 4; ni++)
        acc[mi][ni] = __builtin_amdgcn_mfma_f32_16x16x32_bf16(af[mi], bf[ni], acc[mi][ni], 0, 0, 0);
    __syncthreads();
  }

#pragma unroll
  for (int ni = 0; ni < 4; ni++) {
    int gcol = n0 + wcol + ni * 16 + l16;
    float bval = BIAS ? bias[gcol] : 0.0f;
#pragma unroll
    for (int mi = 0; mi < 4; mi++) {
#pragma unroll
      for (int r = 0; r < 4; r++) {
        int grow = m0 + wrow + mi * 16 + quad * 4 + r;
        float v = acc[mi][ni][r] + bval;
        if (OUTF32) ((float*)Cout)[(size_t)grow * N + gcol] = v;
        else        ((u16*)Cout)[(size_t)grow * N + gcol]   = f2b(v);
      }
    }
  }
}

// ---------- flash attention v3 ----------
// Pipelined K-loop: K double-buffered (prefetch kt+1, wait vmcnt(8)), V single
// buffer staged under QK+softmax (wait vmcnt(4) before PV). Raw s_barrier (no
// vmcnt(0) drain). DPP 16-lane reductions. Q frags global->reg. Balanced
// schedule: block processes qtile pair (i, 31-i) = 33 iterations each.
// LDS: kbuf 2x16KB @0 | vbuf 16KB @16384 | pbuf 8KB @24576 = 56 KB.
// grid: (16, 32 b*h), 512 blocks = 2/CU exactly.
__global__ __launch_bounds__(256, 2) void attn_kernel(
    const u16* __restrict__ Qt, const u16* __restrict__ Kt,
    const u16* __restrict__ Vt, u16* __restrict__ Ob) {
  __shared__ u16 sm[28672];
  u16* vbuf = sm + 16384;
  u16* pbuf = sm + 24576;

  const int bh = blockIdx.y;
  const int b = bh >> 4, h = bh & 15, kv = h >> 2;
  const int tid = threadIdx.x;
  const int lane = tid & 63;
  const int wave = tid >> 6;
  const int quad = lane >> 4;
  const int l16 = lane & 15;

  const u16* qbase = Qt + (size_t)(b * NH + h) * 32 * 8192;
  const u16* kbase = Kt + (size_t)(b * NKV + kv) * 32 * 8192;
  const u16* vbase = Vt + (size_t)(b * NKV + kv) * 32 * 8192;

  const int myrow = wave * 16 + quad * 4;
  const f32x4 zero = {0.f, 0.f, 0.f, 0.f};
  // S scaled into exp2 domain: s2 = s * (1/sqrt(128)) * log2(e)
  const float SC2 = 0.08838834764831845f * 1.4426950408889634f;

  int par = 0;  // LDS K-buffer parity, continuous across both halves

  // preload kt=0 K into kbuf[0]
#pragma unroll
  for (int p = 0; p < 4; p++)
    gload16(kbase + p * 2048 + tid * 8, sm + p * 2048 + tid * 8);

  for (int half = 0; half < 2; ++half) {
    const int qt = half ? (31 - (int)blockIdx.x) : (int)blockIdx.x;
    const int q0 = qt * 64;
    const u16* qtile = qbase + (size_t)qt * 8192;

    // Q fragments straight to registers (coalesced in tiled layout)
    bf16x8 af[4];
#pragma unroll
    for (int kc = 0; kc < 4; kc++)
      af[kc] = *(const bf16x8*)&qtile[(size_t)((kc * 4 + quad) * 64 + wave * 16 + l16) * 8];

    float mrow[4], lrow[4];
#pragma unroll
    for (int r = 0; r < 4; r++) { mrow[r] = -__builtin_inff(); lrow[r] = 0.f; }
    f32x4 o[8];
#pragma unroll
    for (int d = 0; d < 8; d++) o[d] = zero;

    for (int kt = 0; kt <= qt; ++kt) {
      u16* kb_c = sm + par * 8192;
      u16* kb_n = sm + (par ^ 1) * 8192;
      const int ktn = (kt < qt) ? kt + 1 : 0;   // next K tile (tile 0 = next half's first)
      const u16* vsrc = vbase + (size_t)kt * 8192;
      const u16* knxt = kbase + (size_t)ktn * 8192;
      // stage V(kt) (used after QK) + prefetch K(ktn)
#pragma unroll
      for (int p = 0; p < 4; p++)
        gload16(vsrc + p * 2048 + tid * 8, vbuf + p * 2048 + tid * 8);
#pragma unroll
      for (int p = 0; p < 4; p++)
        gload16(knxt + p * 2048 + tid * 8, kb_n + p * 2048 + tid * 8);
      // wait current K (leave V + K-prefetch in flight), sync waves
      asm volatile("s_waitcnt vmcnt(8)\n\ts_barrier" ::: "memory");

      // S = Q K^T : 16 rows x 64 cols per wave
      f32x4 s[4];
#pragma unroll
      for (int nt = 0; nt < 4; nt++) s[nt] = zero;
#pragma unroll
      for (int kc = 0; kc < 4; kc++) {
#pragma unroll
        for (int nt = 0; nt < 4; nt++) {
          bf16x8 bk = *(const bf16x8*)&kb_c[(size_t)((kc * 4 + quad) * 64 + nt * 16 + l16) * 8];
          s[nt] = __builtin_amdgcn_mfma_f32_16x16x32_bf16(af[kc], bk, s[nt], 0, 0, 0);
        }
      }

      float tmax[4];
#pragma unroll
      for (int r = 0; r < 4; r++) tmax[r] = -__builtin_inff();
      if (kt == qt) {
#pragma unroll
        for (int nt = 0; nt < 4; nt++) {
          int colrel = nt * 16 + l16;
#pragma unroll
          for (int r = 0; r < 4; r++) {
            float v = s[nt][r] * SC2;
            if (colrel > myrow + r) v = -__builtin_inff();
            s[nt][r] = v;
            tmax[r] = fmaxf(tmax[r], v);
          }
        }
      } else {
#pragma unroll
        for (int nt = 0; nt < 4; nt++)
#pragma unroll
          for (int r = 0; r < 4; r++) {
            float v = s[nt][r] * SC2;
            s[nt][r] = v;
            tmax[r] = fmaxf(tmax[r], v);
          }
      }
#pragma unroll
      for (int r = 0; r < 4; r++) tmax[r] = red16_max(tmax[r]);

      float alpha[4], lsum[4];
#pragma unroll
      for (int r = 0; r < 4; r++) {
        float mn = fmaxf(mrow[r], tmax[r]);
        alpha[r] = fast_exp2(mrow[r] - mn);
        mrow[r] = mn;
        lsum[r] = 0.f;
      }
      // write P in A-frag tiled layout [kcP 8][row 16][8] per wave
#pragma unroll
      for (int nt = 0; nt < 4; nt++) {
        int kcP = nt * 2 + (l16 >> 3);
#pragma unroll
        for (int r = 0; r < 4; r++) {
          float p = fast_exp2(s[nt][r] - mrow[r]);
          lsum[r] += p;
          pbuf[wave * 1024 + (kcP * 16 + quad * 4 + r) * 8 + (l16 & 7)] = f2b(p);
        }
      }
#pragma unroll
      for (int r = 0; r < 4; r++) lsum[r] = red16_sum(lsum[r]);
#pragma unroll
      for (int r = 0; r < 4; r++) lrow[r] = lrow[r] * alpha[r] + lsum[r];
#pragma unroll
      for (int d = 0; d < 8; d++)
#pragma unroll
        for (int r = 0; r < 4; r++) o[d][r] *= alpha[r];

      // wait V (leave K-prefetch in flight), sync, then PV
      asm volatile("s_waitcnt vmcnt(4)\n\ts_barrier" ::: "memory");
#pragma unroll
      for (int ks = 0; ks < 2; ks++) {
        bf16x8 ap = *(const bf16x8*)&pbuf[(size_t)(wave * 1024 + ((ks * 4 + quad) * 16 + l16) * 8)];
#pragma unroll
        for (int dt = 0; dt < 8; dt++) {
          bf16x8 bv = *(const bf16x8*)&vbuf[(size_t)((ks * 4 + quad) * 128 + dt * 16 + l16) * 8];
          o[dt] = __builtin_amdgcn_mfma_f32_16x16x32_bf16(ap, bv, o[dt], 0, 0, 0);
        }
      }
      // all waves done reading kb_c & vbuf before next iter overwrites
      asm volatile("s_barrier" ::: "memory");
      par ^= 1;
    }

    // epilogue: Ob[b*T + t][h*128 + d] bf16 (row-major, feeds out-GEMM)
    float inv[4];
#pragma unroll
    for (int r = 0; r < 4; r++) inv[r] = 1.0f / lrow[r];
#pragma unroll
    for (int dt = 0; dt < 8; dt++) {
#pragma unroll
      for (int r = 0; r < 4; r++) {
        int t = q0 + myrow + r;
        Ob[(size_t)(b * TT + t) * DMODEL + h * DH + dt * 16 + l16] = f2b(o[dt][r] * inv[r]);
      }
    }
  }
}

// ---------- launcher ----------
extern "C" void kernel_launch(void* const* d_in, const int* in_sizes, int n_in,
                              void* d_out, int out_size, void* d_ws, size_t ws_size,
                              hipStream_t stream) {
  (void)in_sizes; (void)n_in; (void)out_size; (void)ws_size;
  const float* x  = (const float*)d_in[0];
  const float* wq = (const float*)d_in[1];
  const float* bq = (const float*)d_in[2];
  const float* wk = (const float*)d_in[3];
  const float* bk = (const float*)d_in[4];
  const float* wv = (const float*)d_in[5];
  const float* bv = (const float*)d_in[6];
  const float* wo = (const float*)d_in[7];
  float* out = (float*)d_out;

  char* ws = (char*)d_ws;
  u16*   xb    = (u16*)(ws);                       // 16,777,216 B
  u16*   wqkvT = (u16*)(ws + 16777216);            // 12,582,912
  u16*   woT   = (u16*)(ws + 29360128);            //  8,388,608
  float* bcat  = (float*)(ws + 37748736);          //     12,288
  u16*   qkvb  = (u16*)(ws + 37761024);            // 25,165,824
  u16*   qb    = (u16*)(ws + 62926848);            // 16,777,216 (tiled)
  u16*   kb    = (u16*)(ws + 79704064);            //  4,194,304 (tiled)
  u16*   vt    = (u16*)(ws + 83898368);            //  4,194,304 (tiled)
  u16*   ob    = (u16*)(ws + 88092672);            // 16,777,216

  float* outK = out + (size_t)BB * TT * DMODEL;
  float* outV = outK + (size_t)BB * NKV * TT * DH;

  cvt_x_kernel<<<8192, 256, 0, stream>>>(x, xb, (BB * TT * DMODEL) / 4);
  bias_cat_kernel<<<12, 256, 0, stream>>>(bq, bk, bv, bcat);
  transpose_cvt_kernel<<<dim3(32, 32), 256, 0, stream>>>(wq, wqkvT, 2048, 0);
  transpose_cvt_kernel<<<dim3(8, 32),  256, 0, stream>>>(wk, wqkvT, 512, 2048);
  transpose_cvt_kernel<<<dim3(8, 32),  256, 0, stream>>>(wv, wqkvT, 512, 2560);
  transpose_cvt_kernel<<<dim3(32, 32), 256, 0, stream>>>(wo, woT, 2048, 0);

  gemm_kernel<1, 0><<<dim3(NQKV / 128, MM / 128), 256, 0, stream>>>(
      xb, wqkvT, bcat, qkvb, MM, NQKV, DMODEL);

  rope_pack_kernel<<<dim3(TT, BB), 256, 0, stream>>>(qkvb, qb, kb, outK, outV);
  vt_transpose_kernel<<<dim3(TT / 64, DH / 64, BB * NKV), 256, 0, stream>>>(qkvb, vt);

  attn_kernel<<<dim3(16, BB * NH), 256, 0, stream>>>(qb, kb, vt, ob);

  gemm_kernel<0, 1><<<dim3(DMODEL / 128, MM / 128), 256, 0, stream>>>(
      ob, woT, nullptr, out, MM, DMODEL, DMODEL);
}

// Round 4
// 341.975 us; speedup vs baseline: 1.6919x; 1.0231x over previous
//
#include <hip/hip_runtime.h>
#include <hip/hip_bf16.h>
#include <math.h>

// ---------- constants ----------
#define BB 2
#define TT 2048
#define DMODEL 2048
#define NH 16
#define NKV 4
#define DH 128
#define NQKV 3072            // 2048 + 512 + 512
#define MM (BB*TT)           // 4096

typedef unsigned short u16;
typedef unsigned int u32;

typedef __bf16 bf16x8 __attribute__((ext_vector_type(8)));
typedef __bf16 bf16x4 __attribute__((ext_vector_type(4)));
typedef short short4v __attribute__((ext_vector_type(4)));
typedef float f32x4 __attribute__((ext_vector_type(4)));

__device__ __forceinline__ u16 f2b(float f) {
  union { float f; u32 u; } v; v.f = f;
  u32 r = v.u + 0x7fffu + ((v.u >> 16) & 1u);
  return (u16)(r >> 16);
}
__device__ __forceinline__ float b2f(u16 h) {
  union { u32 u; float f; } v; v.u = ((u32)h) << 16;
  return v.f;
}
// pack two floats -> two bf16 in one u32 (round-half-up; P in [0,1], err ~ulp/2)
__device__ __forceinline__ u32 pack2bf(float x, float y) {
  union { float f; u32 u; } a, b; a.f = x; b.f = y;
  return ((a.u + 0x8000u) >> 16) | ((b.u + 0x8000u) & 0xffff0000u);
}

// async global->LDS, 16B per lane
__device__ __forceinline__ void gload16(const void* g, void* l) {
  __builtin_amdgcn_global_load_lds(
      (const __attribute__((address_space(1))) unsigned int*)g,
      (__attribute__((address_space(3))) unsigned int*)l, 16, 0, 0);
}

__device__ __forceinline__ float fast_exp2(float x) {
#if __has_builtin(__builtin_amdgcn_exp2f)
  return __builtin_amdgcn_exp2f(x);
#else
  return __expf(x * 0.6931471805599453f);
#endif
}

// 16x16x16 bf16 MFMA with fallback chain
__device__ __forceinline__ f32x4 mfma16(bf16x4 a, bf16x4 b, f32x4 c) {
#if __has_builtin(__builtin_amdgcn_mfma_f32_16x16x16bf16_1k)
  union { bf16x4 b; short4v s; } ua, ub;
  ua.b = a; ub.b = b;
  return __builtin_amdgcn_mfma_f32_16x16x16bf16_1k(ua.s, ub.s, c, 0, 0, 0);
#elif __has_builtin(__builtin_amdgcn_mfma_f32_16x16x16_bf16)
  return __builtin_amdgcn_mfma_f32_16x16x16_bf16(a, b, c, 0, 0, 0);
#else
  asm volatile("v_mfma_f32_16x16x16_bf16 %0, %1, %2, %0"
               : "+v"(c) : "v"(a), "v"(b));
  return c;
#endif
}

// ---------- elementwise convert x (fp32 -> bf16), 4 elems/thread ----------
__global__ void cvt_x_kernel(const float* __restrict__ x, u16* __restrict__ xb, int n4) {
  int i = blockIdx.x * 256 + threadIdx.x;
  if (i < n4) {
    float4 v = ((const float4*)x)[i];
    u32 lo = (u32)f2b(v.x) | ((u32)f2b(v.y) << 16);
    u32 hi = (u32)f2b(v.z) | ((u32)f2b(v.w) << 16);
    uint2 r; r.x = lo; r.y = hi;
    ((uint2*)xb)[i] = r;
  }
}

// ---------- concat bias ----------
__global__ void bias_cat_kernel(const float* __restrict__ bq, const float* __restrict__ bk,
                                const float* __restrict__ bv, float* __restrict__ bc) {
  int i = blockIdx.x * 256 + threadIdx.x;
  if (i < NQKV) bc[i] = (i < 2048) ? bq[i] : ((i < 2560) ? bk[i - 2048] : bv[i - 2560]);
}

// ---------- transpose + convert weights: src [2048(k) x srcCols(n)] fp32 -> dst[n][k] bf16 ----------
__global__ void transpose_cvt_kernel(const float* __restrict__ src, u16* __restrict__ dst,
                                     int srcCols, int dstRowOff) {
  __shared__ u16 t[64][65];
  int c0 = blockIdx.x * 64, r0 = blockIdx.y * 64;
  int tid = threadIdx.x;
  for (int i = tid; i < 4096; i += 256) {
    int r = i >> 6, c = i & 63;
    t[r][c] = f2b(src[(size_t)(r0 + r) * srcCols + c0 + c]);
  }
  __syncthreads();
  for (int i = tid; i < 4096; i += 256) {
    int n = i >> 6, k = i & 63;
    dst[(size_t)(dstRowOff + c0 + n) * 2048 + r0 + k] = t[k][n];
  }
}

// ---------- transpose V -> vt tiled for PV A-frags ----------
// per 64x128 (s x d) tile: layout [chunk = m*4 + quad][d 128][8] where the 8
// inner values are s = (2m + (e>>2))*16 + quad*4 + (e&3)  (two x16 k-chunks).
__global__ void vt_transpose_kernel(const u16* __restrict__ qkvb, u16* __restrict__ vt) {
  __shared__ u16 t[64][65];
  int bkv = blockIdx.z;                  // b*4+kv
  int b  = bkv >> 2;
  int kv = bkv & 3;
  int d0 = blockIdx.y * 64;
  int t0 = blockIdx.x * 64;
  int tid = threadIdx.x;
  for (int i = tid; i < 4096; i += 256) {
    int r = i >> 6, c = i & 63;  // r = s-local, c = d-local
    t[r][c] = qkvb[(size_t)(b * TT + t0 + r) * NQKV + 2560 + kv * DH + d0 + c];
  }
  __syncthreads();
  size_t tilebase = ((size_t)bkv * 32 + (t0 >> 6)) * 8192;
  for (int i = tid; i < 512; i += 256) {
    int dl = i & 63, chunk = i >> 6;     // chunk = m*4 + quad
    int m = chunk >> 2, qd = chunk & 3;
    u16 tmp[8];
#pragma unroll
    for (int e = 0; e < 8; e++) {
      int srow = (2 * m + (e >> 2)) * 16 + qd * 4 + (e & 3);
      tmp[e] = t[srow][dl];
    }
    *(uint4*)&vt[tilebase + (size_t)(chunk * 128 + d0 + dl) * 8] = *(const uint4*)tmp;
  }
}

// ---------- RoPE + pack kernel (vectorized) ----------
// qkvb [B*T][3072] bf16. qb/kb tiled [b][head][ttile32][kc16][row64][8].
__global__ void rope_pack_kernel(const u16* __restrict__ qkvb, u16* __restrict__ qb,
                                 u16* __restrict__ kb, float* __restrict__ outK,
                                 float* __restrict__ outV) {
  __shared__ float sc_s[64], sc_c[64];
  int t = blockIdx.x, b = blockIdx.y;
  int tid = threadIdx.x;
  if (tid < 64) {
    float inv = exp2f(-(float)tid * 0.31143075889569023f);
    float th = (float)t * inv;
    sc_s[tid] = sinf(th);
    sc_c[tid] = cosf(th);
  }
  __syncthreads();
  const u16* row = qkvb + (size_t)(b * TT + t) * NQKV;
  const int rl = t & 63;        // row-local in 64-tile
  const int tt = t >> 6;        // tile index

  if (tid < 128) {
    // q: task = (h, octet oc); d = oc*8..+7 paired with +64
    int h = tid >> 3, oc = tid & 7;
    uint4 lo = *(const uint4*)&row[h * DH + oc * 8];
    uint4 hi = *(const uint4*)&row[h * DH + 64 + oc * 8];
    const u16* plo = (const u16*)&lo;
    const u16* phi = (const u16*)&hi;
    u16 y1[8], y2[8];
#pragma unroll
    for (int j = 0; j < 8; j++) {
      int d = oc * 8 + j;
      float x1 = b2f(plo[j]), x2 = b2f(phi[j]);
      float s = sc_s[d], c = sc_c[d];
      y1[j] = f2b(c * x1 - s * x2);
      y2[j] = f2b(c * x2 + s * x1);
    }
    size_t tb = ((size_t)(b * NH + h) * 32 + tt) * 8192;
    *(uint4*)&qb[tb + (size_t)((oc)     * 64 + rl) * 8] = *(const uint4*)y1;
    *(uint4*)&qb[tb + (size_t)((oc + 8) * 64 + rl) * 8] = *(const uint4*)y2;
  } else if (tid < 160) {
    int id = tid - 128;
    int kv = id >> 3, oc = id & 7;
    uint4 lo = *(const uint4*)&row[2048 + kv * DH + oc * 8];
    uint4 hi = *(const uint4*)&row[2048 + kv * DH + 64 + oc * 8];
    const u16* plo = (const u16*)&lo;
    const u16* phi = (const u16*)&hi;
    u16 y1[8], y2[8];
    float f1[8], f2v[8];
#pragma unroll
    for (int j = 0; j < 8; j++) {
      int d = oc * 8 + j;
      float x1 = b2f(plo[j]), x2 = b2f(phi[j]);
      float s = sc_s[d], c = sc_c[d];
      f1[j] = c * x1 - s * x2;
      f2v[j] = c * x2 + s * x1;
      y1[j] = f2b(f1[j]);
      y2[j] = f2b(f2v[j]);
    }
    size_t tb = ((size_t)(b * NKV + kv) * 32 + tt) * 8192;
    *(uint4*)&kb[tb + (size_t)((oc)     * 64 + rl) * 8] = *(const uint4*)y1;
    *(uint4*)&kb[tb + (size_t)((oc + 8) * 64 + rl) * 8] = *(const uint4*)y2;
    size_t base = ((size_t)(b * NKV + kv) * TT + t) * DH + oc * 8;
    *(float4*)&outK[base]     = *(const float4*)&f1[0];
    *(float4*)&outK[base + 4] = *(const float4*)&f1[4];
    *(float4*)&outK[base + 64]     = *(const float4*)&f2v[0];
    *(float4*)&outK[base + 64 + 4] = *(const float4*)&f2v[4];
  } else if (tid < 224) {
    int id = tid - 160;
    int kv = id >> 4, oc = id & 15;     // d = oc*8 .. +7 over full 128
    uint4 v = *(const uint4*)&row[2560 + kv * DH + oc * 8];
    const u16* pv = (const u16*)&v;
    float f[8];
#pragma unroll
    for (int j = 0; j < 8; j++) f[j] = b2f(pv[j]);
    size_t base = ((size_t)(b * NKV + kv) * TT + t) * DH + oc * 8;
    *(float4*)&outV[base]     = *(const float4*)&f[0];
    *(float4*)&outV[base + 4] = *(const float4*)&f[4];
  }
}

// ---------- bf16 MFMA GEMM: C[M,N] = A[M,K] @ Bt[N,K]^T (+bias) ----------
template <int BIAS, int OUTF32>
__global__ __launch_bounds__(256, 3) void gemm_kernel(
    const u16* __restrict__ A, const u16* __restrict__ Bt,
    const float* __restrict__ bias, void* __restrict__ Cout,
    int M, int N, int K) {
  __shared__ u16 lA[128 * 32];
  __shared__ u16 lB[128 * 32];
  const int tid  = threadIdx.x;
  const int lane = tid & 63;
  const int wave = tid >> 6;
  const int quad = lane >> 4;
  const int l16  = lane & 15;
  const int m0 = blockIdx.y * 128;
  const int n0 = blockIdx.x * 128;
  const int wrow = (wave >> 1) * 64;
  const int wcol = (wave & 1) * 64;

  f32x4 acc[4][4];
  const f32x4 zero = {0.f, 0.f, 0.f, 0.f};
#pragma unroll
  for (int i = 0; i < 4; i++)
#pragma unroll
    for (int j = 0; j < 4; j++) acc[i][j] = zero;

  const int srow = tid >> 2;
  const int scol = (tid & 3) * 8;

  const u16* ga = A  + (size_t)(m0 + srow) * K + scol;
  const u16* gb = Bt + (size_t)(n0 + srow) * K + scol;

  for (int k0 = 0; k0 < K; k0 += 32) {
    gload16(ga + k0,                  &lA[tid * 8]);
    gload16(ga + k0 + (size_t)64 * K, &lA[2048 + tid * 8]);
    gload16(gb + k0,                  &lB[tid * 8]);
    gload16(gb + k0 + (size_t)64 * K, &lB[2048 + tid * 8]);
    __syncthreads();
    bf16x8 af[4], bf[4];
#pragma unroll
    for (int mi = 0; mi < 4; mi++)
      af[mi] = *(const bf16x8*)&lA[(wrow + mi * 16 + l16) * 32 + quad * 8];
#pragma unroll
    for (int ni = 0; ni < 4; ni++)
      bf[ni] = *(const bf16x8*)&lB[(wcol + ni * 16 + l16) * 32 + quad * 8];
#pragma unroll
    for (int mi = 0; mi < 4; mi++)
#pragma unroll
      for (int ni = 0; ni < 4; ni++)
        acc[mi][ni] = __builtin_amdgcn_mfma_f32_16x16x32_bf16(af[mi], bf[ni], acc[mi][ni], 0, 0, 0);
    __syncthreads();
  }

#pragma unroll
  for (int ni = 0; ni < 4; ni++) {
    int gcol = n0 + wcol + ni * 16 + l16;
    float bval = BIAS ? bias[gcol] : 0.0f;
#pragma unroll
    for (int mi = 0; mi < 4; mi++) {
#pragma unroll
      for (int r = 0; r < 4; r++) {
        int grow = m0 + wrow + mi * 16 + quad * 4 + r;
        float v = acc[mi][ni][r] + bval;
        if (OUTF32) ((float*)Cout)[(size_t)grow * N + gcol] = v;
        else        ((u16*)Cout)[(size_t)grow * N + gcol]   = f2b(v);
      }
    }
  }
}

// ---------- flash attention v4: transposed compute ----------
// S^T = K Q^T via mfma 16x16x32 (A=K, B=Q): lane holds q = l16 (scalar softmax
// state), 16 s-values (4 mt x 4 reg). PV: O^T = V^T P^T via mfma 16x16x16 with
// P^T fed straight from registers (no LDS round-trip). K double-buffered with
// vmcnt(8); V single buffer waited at vmcnt(4). Balanced qtile pairs (i,31-i).
// LDS: kbuf 2x16KB | vbuf 16KB = 48 KB. grid (16, 32) = 512 blocks = 2/CU.
__global__ __launch_bounds__(256, 2) void attn_kernel(
    const u16* __restrict__ Qt, const u16* __restrict__ Kt,
    const u16* __restrict__ Vt, u16* __restrict__ Ob) {
  __shared__ u16 sm[24576];
  u16* vbuf = sm + 16384;

  const int bh = blockIdx.y;
  const int b = bh >> 4, h = bh & 15, kv = h >> 2;
  const int tid = threadIdx.x;
  const int lane = tid & 63;
  const int wave = tid >> 6;
  const int quad = lane >> 4;
  const int l16 = lane & 15;

  const u16* qbase = Qt + (size_t)(b * NH + h) * 32 * 8192;
  const u16* kbase = Kt + (size_t)(b * NKV + kv) * 32 * 8192;
  const u16* vbase = Vt + (size_t)(b * NKV + kv) * 32 * 8192;

  const f32x4 zero = {0.f, 0.f, 0.f, 0.f};
  const float SC2 = 0.08838834764831845f * 1.4426950408889634f;  // scale*log2e
  const float NEGINF = -__builtin_inff();

  int par = 0;  // K LDS buffer parity, continuous across both halves

  // preload kt=0 K into kbuf[0]
#pragma unroll
  for (int p = 0; p < 4; p++)
    gload16(kbase + p * 2048 + tid * 8, sm + p * 2048 + tid * 8);

  for (int half = 0; half < 2; ++half) {
    const int qt = half ? (31 - (int)blockIdx.x) : (int)blockIdx.x;
    const int q0 = qt * 64;
    const u16* qtile = qbase + (size_t)qt * 8192;
    const int qrel = wave * 16 + l16;    // this lane's q (block-relative)

    // Q B-fragments straight to registers
    bf16x8 qf[4];
#pragma unroll
    for (int kc = 0; kc < 4; kc++)
      qf[kc] = *(const bf16x8*)&qtile[(size_t)((kc * 4 + quad) * 64 + qrel) * 8];

    float mrow = NEGINF, lrow = 0.f;
    f32x4 o[8];
#pragma unroll
    for (int d = 0; d < 8; d++) o[d] = zero;

    for (int kt = 0; kt <= qt; ++kt) {
      u16* kb_c = sm + par * 8192;
      u16* kb_n = sm + (par ^ 1) * 8192;
      const int ktn = (kt < qt) ? kt + 1 : 0;
      const u16* vsrc = vbase + (size_t)kt * 8192;
      const u16* knxt = kbase + (size_t)ktn * 8192;
#pragma unroll
      for (int p = 0; p < 4; p++)
        gload16(vsrc + p * 2048 + tid * 8, vbuf + p * 2048 + tid * 8);
#pragma unroll
      for (int p = 0; p < 4; p++)
        gload16(knxt + p * 2048 + tid * 8, kb_n + p * 2048 + tid * 8);
      asm volatile("s_waitcnt vmcnt(8)\n\ts_barrier" ::: "memory");

      // S^T = K Q^T : rows s (4 mt tiles), cols q (16, = l16)
      f32x4 sv[4];
#pragma unroll
      for (int mt = 0; mt < 4; mt++) sv[mt] = zero;
#pragma unroll
      for (int kc = 0; kc < 4; kc++) {
#pragma unroll
        for (int mt = 0; mt < 4; mt++) {
          bf16x8 kf = *(const bf16x8*)&kb_c[(size_t)((kc * 4 + quad) * 64 + mt * 16 + l16) * 8];
          sv[mt] = __builtin_amdgcn_mfma_f32_16x16x32_bf16(kf, qf[kc], sv[mt], 0, 0, 0);
        }
      }

      // causal mask on diagonal tile: s_rel > q_rel masked
      if (kt == qt) {
#pragma unroll
        for (int mt = 0; mt < 4; mt++) {
#pragma unroll
          for (int r = 0; r < 4; r++) {
            int srel = mt * 16 + quad * 4 + r;
            if (srel > qrel) sv[mt][r] = NEGINF;
          }
        }
      }
      // row max over 64 s for this lane's q: 16 in-lane + cross-quad
      float mraw = NEGINF;
#pragma unroll
      for (int mt = 0; mt < 4; mt++)
#pragma unroll
        for (int r = 0; r < 4; r++) mraw = fmaxf(mraw, sv[mt][r]);
      mraw = fmaxf(mraw, __shfl_xor(mraw, 16));
      mraw = fmaxf(mraw, __shfl_xor(mraw, 32));

      float mnew = fmaxf(mrow, mraw);
      float alpha = fast_exp2((mrow - mnew) * SC2);
      mrow = mnew;
      float msc = mnew * SC2;
      float lsum = 0.f;
#pragma unroll
      for (int mt = 0; mt < 4; mt++) {
#pragma unroll
        for (int r = 0; r < 4; r++) {
          float p = fast_exp2(__builtin_fmaf(sv[mt][r], SC2, -msc));
          sv[mt][r] = p;
          lsum += p;
        }
      }
      lsum += __shfl_xor(lsum, 16);
      lsum += __shfl_xor(lsum, 32);
      lrow = lrow * alpha + lsum;
      // pack P^T fragments (B-operand of 16x16x16: k = quad*4 + j)
      bf16x4 pb[4];
#pragma unroll
      for (int mt = 0; mt < 4; mt++) {
        union { u32 u[2]; bf16x4 v; } pu;
        pu.u[0] = pack2bf(sv[mt][0], sv[mt][1]);
        pu.u[1] = pack2bf(sv[mt][2], sv[mt][3]);
        pb[mt] = pu.v;
      }
#pragma unroll
      for (int dt = 0; dt < 8; dt++) {
        o[dt][0] *= alpha; o[dt][1] *= alpha; o[dt][2] *= alpha; o[dt][3] *= alpha;
      }

      asm volatile("s_waitcnt vmcnt(4)\n\ts_barrier" ::: "memory");
      // PV: O^T[d][q] += V^T[d][s] P^T[s][q], 16x16x16, A-frags from vbuf
#pragma unroll
      for (int m = 0; m < 2; m++) {
#pragma unroll
        for (int dt = 0; dt < 8; dt++) {
          bf16x8 vf = *(const bf16x8*)&vbuf[(size_t)(((m * 4 + quad) * 128) + dt * 16 + l16) * 8];
          bf16x4 vlo = __builtin_shufflevector(vf, vf, 0, 1, 2, 3);
          bf16x4 vhi = __builtin_shufflevector(vf, vf, 4, 5, 6, 7);
          o[dt] = mfma16(vlo, pb[2 * m],     o[dt]);
          o[dt] = mfma16(vhi, pb[2 * m + 1], o[dt]);
        }
      }
      asm volatile("s_barrier" ::: "memory");
      par ^= 1;
    }

    // epilogue: O^T lane holds q = qrel (t-row), d = dt*16 + quad*4 + r
    float inv = 1.0f / lrow;
    int t = q0 + qrel;
    size_t rowbase = (size_t)(b * TT + t) * DMODEL + h * DH;
#pragma unroll
    for (int dt = 0; dt < 8; dt++) {
      uint2 w;
      w.x = pack2bf(o[dt][0] * inv, o[dt][1] * inv);
      w.y = pack2bf(o[dt][2] * inv, o[dt][3] * inv);
      *(uint2*)&Ob[rowbase + dt * 16 + quad * 4] = w;
    }
  }
}

// ---------- launcher ----------
extern "C" void kernel_launch(void* const* d_in, const int* in_sizes, int n_in,
                              void* d_out, int out_size, void* d_ws, size_t ws_size,
                              hipStream_t stream) {
  (void)in_sizes; (void)n_in; (void)out_size; (void)ws_size;
  const float* x  = (const float*)d_in[0];
  const float* wq = (const float*)d_in[1];
  const float* bq = (const float*)d_in[2];
  const float* wk = (const float*)d_in[3];
  const float* bk = (const float*)d_in[4];
  const float* wv = (const float*)d_in[5];
  const float* bv = (const float*)d_in[6];
  const float* wo = (const float*)d_in[7];
  float* out = (float*)d_out;

  char* ws = (char*)d_ws;
  u16*   xb    = (u16*)(ws);                       // 16,777,216 B
  u16*   wqkvT = (u16*)(ws + 16777216);            // 12,582,912
  u16*   woT   = (u16*)(ws + 29360128);            //  8,388,608
  float* bcat  = (float*)(ws + 37748736);          //     12,288
  u16*   qkvb  = (u16*)(ws + 37761024);            // 25,165,824
  u16*   qb    = (u16*)(ws + 62926848);            // 16,777,216 (tiled)
  u16*   kb    = (u16*)(ws + 79704064);            //  4,194,304 (tiled)
  u16*   vt    = (u16*)(ws + 83898368);            //  4,194,304 (tiled, PV-perm)
  u16*   ob    = (u16*)(ws + 88092672);            // 16,777,216

  float* outK = out + (size_t)BB * TT * DMODEL;
  float* outV = outK + (size_t)BB * NKV * TT * DH;

  cvt_x_kernel<<<8192, 256, 0, stream>>>(x, xb, (BB * TT * DMODEL) / 4);
  bias_cat_kernel<<<12, 256, 0, stream>>>(bq, bk, bv, bcat);
  transpose_cvt_kernel<<<dim3(32, 32), 256, 0, stream>>>(wq, wqkvT, 2048, 0);
  transpose_cvt_kernel<<<dim3(8, 32),  256, 0, stream>>>(wk, wqkvT, 512, 2048);
  transpose_cvt_kernel<<<dim3(8, 32),  256, 0, stream>>>(wv, wqkvT, 512, 2560);
  transpose_cvt_kernel<<<dim3(32, 32), 256, 0, stream>>>(wo, woT, 2048, 0);

  gemm_kernel<1, 0><<<dim3(NQKV / 128, MM / 128), 256, 0, stream>>>(
      xb, wqkvT, bcat, qkvb, MM, NQKV, DMODEL);

  rope_pack_kernel<<<dim3(TT, BB), 256, 0, stream>>>(qkvb, qb, kb, outK, outV);
  vt_transpose_kernel<<<dim3(TT / 64, DH / 64, BB * NKV), 256, 0, stream>>>(qkvb, vt);

  attn_kernel<<<dim3(16, BB * NH), 256, 0, stream>>>(qb, kb, vt, ob);

  gemm_kernel<0, 1><<<dim3(DMODEL / 128, MM / 128), 256, 0, stream>>>(
      ob, woT, nullptr, out, MM, DMODEL, DMODEL);
}

// Round 5
// 315.355 us; speedup vs baseline: 1.8347x; 1.0844x over previous
//
#include <hip/hip_runtime.h>
#include <hip/hip_bf16.h>
#include <math.h>

// ---------- constants ----------
#define BB 2
#define TT 2048
#define DMODEL 2048
#define NH 16
#define NKV 4
#define DH 128
#define NQKV 3072            // 2048 + 512 + 512
#define MM (BB*TT)           // 4096

typedef unsigned short u16;
typedef unsigned int u32;

typedef __bf16 bf16x8 __attribute__((ext_vector_type(8)));
typedef __bf16 bf16x4 __attribute__((ext_vector_type(4)));
typedef short short4v __attribute__((ext_vector_type(4)));
typedef float f32x4 __attribute__((ext_vector_type(4)));

__device__ __forceinline__ u16 f2b(float f) {
  union { float f; u32 u; } v; v.f = f;
  u32 r = v.u + 0x7fffu + ((v.u >> 16) & 1u);
  return (u16)(r >> 16);
}
__device__ __forceinline__ float b2f(u16 h) {
  union { u32 u; float f; } v; v.u = ((u32)h) << 16;
  return v.f;
}
__device__ __forceinline__ u32 pack2bf(float x, float y) {
  union { float f; u32 u; } a, b; a.f = x; b.f = y;
  return ((a.u + 0x8000u) >> 16) | ((b.u + 0x8000u) & 0xffff0000u);
}

// async global->LDS, 16B per lane
__device__ __forceinline__ void gload16(const void* g, void* l) {
  __builtin_amdgcn_global_load_lds(
      (const __attribute__((address_space(1))) unsigned int*)g,
      (__attribute__((address_space(3))) unsigned int*)l, 16, 0, 0);
}

__device__ __forceinline__ float fast_exp2(float x) {
#if __has_builtin(__builtin_amdgcn_exp2f)
  return __builtin_amdgcn_exp2f(x);
#else
  return __expf(x * 0.6931471805599453f);
#endif
}

// 16x16x16 bf16 MFMA with fallback chain
__device__ __forceinline__ f32x4 mfma16(bf16x4 a, bf16x4 b, f32x4 c) {
#if __has_builtin(__builtin_amdgcn_mfma_f32_16x16x16bf16_1k)
  union { bf16x4 b; short4v s; } ua, ub;
  ua.b = a; ub.b = b;
  return __builtin_amdgcn_mfma_f32_16x16x16bf16_1k(ua.s, ub.s, c, 0, 0, 0);
#elif __has_builtin(__builtin_amdgcn_mfma_f32_16x16x16_bf16)
  return __builtin_amdgcn_mfma_f32_16x16x16_bf16(a, b, c, 0, 0, 0);
#else
  asm volatile("v_mfma_f32_16x16x16_bf16 %0, %1, %2, %0"
               : "+v"(c) : "v"(a), "v"(b));
  return c;
#endif
}

// ---------- elementwise convert x (fp32 -> bf16), 4 elems/thread ----------
__global__ void cvt_x_kernel(const float* __restrict__ x, u16* __restrict__ xb, int n4) {
  int i = blockIdx.x * 256 + threadIdx.x;
  if (i < n4) {
    float4 v = ((const float4*)x)[i];
    u32 lo = (u32)f2b(v.x) | ((u32)f2b(v.y) << 16);
    u32 hi = (u32)f2b(v.z) | ((u32)f2b(v.w) << 16);
    uint2 r; r.x = lo; r.y = hi;
    ((uint2*)xb)[i] = r;
  }
}

// ---------- rope table: [T][64] (cos, sin) fp32 ----------
__global__ void rope_table_kernel(float2* __restrict__ tab) {
  int i = blockIdx.x * 256 + threadIdx.x;   // T*64 = 131072
  int t = i >> 6, d = i & 63;
  float inv = exp2f(-(float)d * 0.31143075889569023f);  // 1e6^(-d/64)
  float th = (float)t * inv;
  float2 cs; cs.x = cosf(th); cs.y = sinf(th);
  tab[i] = cs;
}

// ---------- transpose + convert weights: src [2048(k) x srcCols(n)] fp32 -> dst[n][k] bf16 ----------
__global__ void transpose_cvt_kernel(const float* __restrict__ src, u16* __restrict__ dst,
                                     int srcCols, int dstRowOff) {
  __shared__ u16 t[64][65];
  int c0 = blockIdx.x * 64, r0 = blockIdx.y * 64;
  int tid = threadIdx.x;
  for (int i = tid; i < 4096; i += 256) {
    int r = i >> 6, c = i & 63;
    t[r][c] = f2b(src[(size_t)(r0 + r) * srcCols + c0 + c]);
  }
  __syncthreads();
  for (int i = tid; i < 4096; i += 256) {
    int n = i >> 6, k = i & 63;
    dst[(size_t)(dstRowOff + c0 + n) * 2048 + r0 + k] = t[k][n];
  }
}

// ---------- fused QKV GEMM + bias + RoPE + layout pack ----------
// C[M,3072] = xb[M,2048] @ wqkvT^T. n-tile(128) == one head. Pipelined K-loop
// (dbuf LDS, vmcnt(4) hold, no drain). Epilogue: C tile -> LDS (bf16, reusing
// staging bufs), then per head class: Q -> rope -> qb tiled; K -> rope -> kb
// tiled + outK fp32; V -> outV fp32 + vt tiled (PV-perm).
__global__ __launch_bounds__(256, 3) void gemm_qkv_kernel(
    const u16* __restrict__ A, const u16* __restrict__ Bt,
    const float* __restrict__ bq, const float* __restrict__ bk,
    const float* __restrict__ bv, const float2* __restrict__ rtab,
    u16* __restrict__ qb, u16* __restrict__ kb, u16* __restrict__ vt,
    float* __restrict__ outK, float* __restrict__ outV) {
  // 32 KB union: dbuf staging (2 x (A 8KB | B 8KB)) then C tile 128x128 bf16
  __shared__ __align__(16) u16 sm[16384];
  const int K = DMODEL;
  const int tid  = threadIdx.x;
  const int lane = tid & 63;
  const int wave = tid >> 6;
  const int quad = lane >> 4;
  const int l16  = lane & 15;
  const int m0 = blockIdx.y * 128;
  const int n0 = blockIdx.x * 128;
  const int nh = blockIdx.x;           // head-class index (0..23)
  const int wrow = (wave >> 1) * 64;
  const int wcol = (wave & 1) * 64;

  f32x4 acc[4][4];
  const f32x4 zero = {0.f, 0.f, 0.f, 0.f};
#pragma unroll
  for (int i = 0; i < 4; i++)
#pragma unroll
    for (int j = 0; j < 4; j++) acc[i][j] = zero;

  const int srow = tid >> 2;
  const int scol = (tid & 3) * 8;
  const u16* ga = A  + (size_t)(m0 + srow) * K + scol;
  const u16* gb = Bt + (size_t)(n0 + srow) * K + scol;

  // prologue: stage k0=0 into buf 0
  gload16(ga,                  &sm[tid * 8]);
  gload16(ga + (size_t)64 * K, &sm[2048 + tid * 8]);
  gload16(gb,                  &sm[4096 + tid * 8]);
  gload16(gb + (size_t)64 * K, &sm[6144 + tid * 8]);

  for (int k0 = 0; k0 < K; k0 += 32) {
    const int p = (k0 >> 5) & 1;
    const int kn = (k0 + 32 == K) ? 0 : k0 + 32;
    u16* nb = &sm[(p ^ 1) * 8192];
    gload16(ga + kn,                  nb + tid * 8);
    gload16(ga + kn + (size_t)64 * K, nb + 2048 + tid * 8);
    gload16(gb + kn,                  nb + 4096 + tid * 8);
    gload16(gb + kn + (size_t)64 * K, nb + 6144 + tid * 8);
    asm volatile("s_waitcnt vmcnt(4)\n\ts_barrier" ::: "memory");
    const u16* cb = &sm[p * 8192];
    bf16x8 af[4], bf[4];
#pragma unroll
    for (int mi = 0; mi < 4; mi++)
      af[mi] = *(const bf16x8*)&cb[(wrow + mi * 16 + l16) * 32 + quad * 8];
#pragma unroll
    for (int ni = 0; ni < 4; ni++)
      bf[ni] = *(const bf16x8*)&cb[4096 + (wcol + ni * 16 + l16) * 32 + quad * 8];
    asm volatile("s_waitcnt lgkmcnt(0)\n\ts_barrier" ::: "memory");
#pragma unroll
    for (int mi = 0; mi < 4; mi++)
#pragma unroll
      for (int ni = 0; ni < 4; ni++)
        acc[mi][ni] = __builtin_amdgcn_mfma_f32_16x16x32_bf16(af[mi], bf[ni], acc[mi][ni], 0, 0, 0);
  }

  // drain stray prefetch before reusing LDS as C tile
  asm volatile("s_waitcnt vmcnt(0)\n\ts_barrier" ::: "memory");

  // write C (+bias) as bf16 into ctile[row 128][col 128]
#pragma unroll
  for (int ni = 0; ni < 4; ni++) {
    int col = wcol + ni * 16 + l16;
    int gcol = n0 + col;
    float bval = (nh < 16) ? bq[gcol] : ((nh < 20) ? bk[gcol - 2048] : bv[gcol - 2560]);
#pragma unroll
    for (int mi = 0; mi < 4; mi++) {
#pragma unroll
      for (int r = 0; r < 4; r++) {
        int row = wrow + mi * 16 + quad * 4 + r;
        sm[row * 128 + col] = f2b(acc[mi][ni][r] + bval);
      }
    }
  }
  __syncthreads();

  const int bidx = m0 >> 11;       // batch index (tile never straddles batches)
  const int trow0 = m0 & 2047;

  if (nh < 20) {
    // Q or K head: rope pairs (d, d+64), write tiled layout
    const int isQ = (nh < 16);
    const int hh = isQ ? nh : (nh - 16);
#pragma unroll
    for (int it = 0; it < 4; it++) {
      int id = tid + it * 256;           // 1024 tasks: 128 rows x 8 octets
      int row = id >> 3, oc = id & 7;
      int t = trow0 + row;
      int rl = t & 63, ttile = t >> 6;
      uint4 lo = *(const uint4*)&sm[row * 128 + oc * 8];
      uint4 hi = *(const uint4*)&sm[row * 128 + 64 + oc * 8];
      const u16* plo = (const u16*)&lo;
      const u16* phi = (const u16*)&hi;
      u16 y1[8], y2[8];
      float f1[8], f2v[8];
#pragma unroll
      for (int j = 0; j < 8; j++) {
        float2 cs = rtab[(t << 6) + oc * 8 + j];
        float x1 = b2f(plo[j]), x2 = b2f(phi[j]);
        f1[j]  = cs.x * x1 - cs.y * x2;
        f2v[j] = cs.x * x2 + cs.y * x1;
        y1[j] = f2b(f1[j]);
        y2[j] = f2b(f2v[j]);
      }
      if (isQ) {
        size_t tb = ((size_t)(bidx * NH + hh) * 32 + ttile) * 8192;
        *(uint4*)&qb[tb + (size_t)((oc)     * 64 + rl) * 8] = *(const uint4*)y1;
        *(uint4*)&qb[tb + (size_t)((oc + 8) * 64 + rl) * 8] = *(const uint4*)y2;
      } else {
        size_t tb = ((size_t)(bidx * NKV + hh) * 32 + ttile) * 8192;
        *(uint4*)&kb[tb + (size_t)((oc)     * 64 + rl) * 8] = *(const uint4*)y1;
        *(uint4*)&kb[tb + (size_t)((oc + 8) * 64 + rl) * 8] = *(const uint4*)y2;
        size_t base = ((size_t)(bidx * NKV + hh) * TT + t) * DH + oc * 8;
        *(float4*)&outK[base]          = *(const float4*)&f1[0];
        *(float4*)&outK[base + 4]      = *(const float4*)&f1[4];
        *(float4*)&outK[base + 64]     = *(const float4*)&f2v[0];
        *(float4*)&outK[base + 64 + 4] = *(const float4*)&f2v[4];
      }
    }
  } else {
    // V head: outV fp32 + vt tiled (PV A-frag permutation)
    const int kvh = nh - 20;
#pragma unroll
    for (int it = 0; it < 8; it++) {
      int id = tid + it * 256;           // 2048 tasks: 128 rows x 16 octets
      int row = id >> 4, oc = id & 15;
      uint4 v = *(const uint4*)&sm[row * 128 + oc * 8];
      const u16* pv = (const u16*)&v;
      float f[8];
#pragma unroll
      for (int j = 0; j < 8; j++) f[j] = b2f(pv[j]);
      size_t base = ((size_t)(bidx * NKV + kvh) * TT + trow0 + row) * DH + oc * 8;
      *(float4*)&outV[base]     = *(const float4*)&f[0];
      *(float4*)&outV[base + 4] = *(const float4*)&f[4];
    }
#pragma unroll
    for (int it = 0; it < 8; it++) {
      int id = tid + it * 256;           // 2048 tasks: 2 stiles x 8 chunks x 128 d
      int tile = id >> 10, rem = id & 1023;
      int chunk = rem >> 7, dl = rem & 127;
      int m = chunk >> 2, qd = chunk & 3;
      u16 tmp[8];
#pragma unroll
      for (int e = 0; e < 8; e++) {
        int srw = (2 * m + (e >> 2)) * 16 + qd * 4 + (e & 3);
        tmp[e] = sm[(tile * 64 + srw) * 128 + dl];
      }
      int tt = (trow0 >> 6) + tile;
      size_t tilebase = ((size_t)(bidx * NKV + kvh) * 32 + tt) * 8192;
      *(uint4*)&vt[tilebase + (size_t)(chunk * 128 + dl) * 8] = *(const uint4*)tmp;
    }
  }
}

// ---------- output-projection GEMM (pipelined): out[M,2048] fp32 ----------
__global__ __launch_bounds__(256, 3) void gemm_out_kernel(
    const u16* __restrict__ A, const u16* __restrict__ Bt,
    float* __restrict__ Cout, int M, int N, int K) {
  __shared__ __align__(16) u16 sm[16384];
  const int tid  = threadIdx.x;
  const int lane = tid & 63;
  const int wave = tid >> 6;
  const int quad = lane >> 4;
  const int l16  = lane & 15;
  const int m0 = blockIdx.y * 128;
  const int n0 = blockIdx.x * 128;
  const int wrow = (wave >> 1) * 64;
  const int wcol = (wave & 1) * 64;

  f32x4 acc[4][4];
  const f32x4 zero = {0.f, 0.f, 0.f, 0.f};
#pragma unroll
  for (int i = 0; i < 4; i++)
#pragma unroll
    for (int j = 0; j < 4; j++) acc[i][j] = zero;

  const int srow = tid >> 2;
  const int scol = (tid & 3) * 8;
  const u16* ga = A  + (size_t)(m0 + srow) * K + scol;
  const u16* gb = Bt + (size_t)(n0 + srow) * K + scol;

  gload16(ga,                  &sm[tid * 8]);
  gload16(ga + (size_t)64 * K, &sm[2048 + tid * 8]);
  gload16(gb,                  &sm[4096 + tid * 8]);
  gload16(gb + (size_t)64 * K, &sm[6144 + tid * 8]);

  for (int k0 = 0; k0 < K; k0 += 32) {
    const int p = (k0 >> 5) & 1;
    const int kn = (k0 + 32 == K) ? 0 : k0 + 32;
    u16* nb = &sm[(p ^ 1) * 8192];
    gload16(ga + kn,                  nb + tid * 8);
    gload16(ga + kn + (size_t)64 * K, nb + 2048 + tid * 8);
    gload16(gb + kn,                  nb + 4096 + tid * 8);
    gload16(gb + kn + (size_t)64 * K, nb + 6144 + tid * 8);
    asm volatile("s_waitcnt vmcnt(4)\n\ts_barrier" ::: "memory");
    const u16* cb = &sm[p * 8192];
    bf16x8 af[4], bf[4];
#pragma unroll
    for (int mi = 0; mi < 4; mi++)
      af[mi] = *(const bf16x8*)&cb[(wrow + mi * 16 + l16) * 32 + quad * 8];
#pragma unroll
    for (int ni = 0; ni < 4; ni++)
      bf[ni] = *(const bf16x8*)&cb[4096 + (wcol + ni * 16 + l16) * 32 + quad * 8];
    asm volatile("s_waitcnt lgkmcnt(0)\n\ts_barrier" ::: "memory");
#pragma unroll
    for (int mi = 0; mi < 4; mi++)
#pragma unroll
      for (int ni = 0; ni < 4; ni++)
        acc[mi][ni] = __builtin_amdgcn_mfma_f32_16x16x32_bf16(af[mi], bf[ni], acc[mi][ni], 0, 0, 0);
  }
  asm volatile("s_waitcnt vmcnt(0)" ::: "memory");

#pragma unroll
  for (int ni = 0; ni < 4; ni++) {
    int gcol = n0 + wcol + ni * 16 + l16;
#pragma unroll
    for (int mi = 0; mi < 4; mi++) {
#pragma unroll
      for (int r = 0; r < 4; r++) {
        int grow = m0 + wrow + mi * 16 + quad * 4 + r;
        Cout[(size_t)grow * N + gcol] = acc[mi][ni][r];
      }
    }
  }
}

// ---------- flash attention v4.1: transposed compute, deferred l-reduction ----------
__global__ __launch_bounds__(256, 2) void attn_kernel(
    const u16* __restrict__ Qt, const u16* __restrict__ Kt,
    const u16* __restrict__ Vt, u16* __restrict__ Ob) {
  __shared__ __align__(16) u16 sm[24576];
  u16* vbuf = sm + 16384;

  const int bh = blockIdx.y;
  const int b = bh >> 4, h = bh & 15, kv = h >> 2;
  const int tid = threadIdx.x;
  const int lane = tid & 63;
  const int wave = tid >> 6;
  const int quad = lane >> 4;
  const int l16 = lane & 15;

  const u16* qbase = Qt + (size_t)(b * NH + h) * 32 * 8192;
  const u16* kbase = Kt + (size_t)(b * NKV + kv) * 32 * 8192;
  const u16* vbase = Vt + (size_t)(b * NKV + kv) * 32 * 8192;

  const f32x4 zero = {0.f, 0.f, 0.f, 0.f};
  const float SC2 = 0.08838834764831845f * 1.4426950408889634f;  // scale*log2e
  const float NEGINF = -__builtin_inff();

  int par = 0;

#pragma unroll
  for (int p = 0; p < 4; p++)
    gload16(kbase + p * 2048 + tid * 8, sm + p * 2048 + tid * 8);

  for (int half = 0; half < 2; ++half) {
    const int qt = half ? (31 - (int)blockIdx.x) : (int)blockIdx.x;
    const int q0 = qt * 64;
    const u16* qtile = qbase + (size_t)qt * 8192;
    const int qrel = wave * 16 + l16;

    bf16x8 qf[4];
#pragma unroll
    for (int kc = 0; kc < 4; kc++)
      qf[kc] = *(const bf16x8*)&qtile[(size_t)((kc * 4 + quad) * 64 + qrel) * 8];

    float mrow = NEGINF, lrow = 0.f;   // lrow = per-lane partial (reduced at end)
    f32x4 o[8];
#pragma unroll
    for (int d = 0; d < 8; d++) o[d] = zero;

    for (int kt = 0; kt <= qt; ++kt) {
      u16* kb_c = sm + par * 8192;
      u16* kb_n = sm + (par ^ 1) * 8192;
      const int ktn = (kt < qt) ? kt + 1 : 0;
      const u16* vsrc = vbase + (size_t)kt * 8192;
      const u16* knxt = kbase + (size_t)ktn * 8192;
#pragma unroll
      for (int p = 0; p < 4; p++)
        gload16(vsrc + p * 2048 + tid * 8, vbuf + p * 2048 + tid * 8);
#pragma unroll
      for (int p = 0; p < 4; p++)
        gload16(knxt + p * 2048 + tid * 8, kb_n + p * 2048 + tid * 8);
      asm volatile("s_waitcnt vmcnt(8)\n\ts_barrier" ::: "memory");

      f32x4 sv[4];
#pragma unroll
      for (int mt = 0; mt < 4; mt++) sv[mt] = zero;
#pragma unroll
      for (int kc = 0; kc < 4; kc++) {
#pragma unroll
        for (int mt = 0; mt < 4; mt++) {
          bf16x8 kf = *(const bf16x8*)&kb_c[(size_t)((kc * 4 + quad) * 64 + mt * 16 + l16) * 8];
          sv[mt] = __builtin_amdgcn_mfma_f32_16x16x32_bf16(kf, qf[kc], sv[mt], 0, 0, 0);
        }
      }

      if (kt == qt) {
#pragma unroll
        for (int mt = 0; mt < 4; mt++)
#pragma unroll
          for (int r = 0; r < 4; r++) {
            int srel = mt * 16 + quad * 4 + r;
            if (srel > qrel) sv[mt][r] = NEGINF;
          }
      }
      float mraw = NEGINF;
#pragma unroll
      for (int mt = 0; mt < 4; mt++)
#pragma unroll
        for (int r = 0; r < 4; r++) mraw = fmaxf(mraw, sv[mt][r]);
      mraw = fmaxf(mraw, __shfl_xor(mraw, 16));
      mraw = fmaxf(mraw, __shfl_xor(mraw, 32));

      float mnew = fmaxf(mrow, mraw);
      float alpha = fast_exp2((mrow - mnew) * SC2);  // quad-uniform per q
      mrow = mnew;
      float msc = mnew * SC2;
      float lsum = 0.f;
#pragma unroll
      for (int mt = 0; mt < 4; mt++) {
#pragma unroll
        for (int r = 0; r < 4; r++) {
          float p = fast_exp2(__builtin_fmaf(sv[mt][r], SC2, -msc));
          sv[mt][r] = p;
          lsum += p;
        }
      }
      lrow = lrow * alpha + lsum;      // per-lane partial; no shuffle here
      bf16x4 pb[4];
#pragma unroll
      for (int mt = 0; mt < 4; mt++) {
        union { u32 u[2]; bf16x4 v; } pu;
        pu.u[0] = pack2bf(sv[mt][0], sv[mt][1]);
        pu.u[1] = pack2bf(sv[mt][2], sv[mt][3]);
        pb[mt] = pu.v;
      }
#pragma unroll
      for (int dt = 0; dt < 8; dt++) {
        o[dt][0] *= alpha; o[dt][1] *= alpha; o[dt][2] *= alpha; o[dt][3] *= alpha;
      }

      asm volatile("s_waitcnt vmcnt(4)\n\ts_barrier" ::: "memory");
#pragma unroll
      for (int m = 0; m < 2; m++) {
#pragma unroll
        for (int dt = 0; dt < 8; dt++) {
          bf16x8 vf = *(const bf16x8*)&vbuf[(size_t)(((m * 4 + quad) * 128) + dt * 16 + l16) * 8];
          bf16x4 vlo = __builtin_shufflevector(vf, vf, 0, 1, 2, 3);
          bf16x4 vhi = __builtin_shufflevector(vf, vf, 4, 5, 6, 7);
          o[dt] = mfma16(vlo, pb[2 * m],     o[dt]);
          o[dt] = mfma16(vhi, pb[2 * m + 1], o[dt]);
        }
      }
      asm volatile("s_barrier" ::: "memory");
      par ^= 1;
    }

    // reduce deferred l across quads, then write O^T
    lrow += __shfl_xor(lrow, 16);
    lrow += __shfl_xor(lrow, 32);
    float inv = 1.0f / lrow;
    int t = q0 + qrel;
    size_t rowbase = (size_t)(b * TT + t) * DMODEL + h * DH;
#pragma unroll
    for (int dt = 0; dt < 8; dt++) {
      uint2 w;
      w.x = pack2bf(o[dt][0] * inv, o[dt][1] * inv);
      w.y = pack2bf(o[dt][2] * inv, o[dt][3] * inv);
      *(uint2*)&Ob[rowbase + dt * 16 + quad * 4] = w;
    }
  }
  asm volatile("s_waitcnt vmcnt(0)" ::: "memory");   // drain stray prefetch
}

// ---------- launcher ----------
extern "C" void kernel_launch(void* const* d_in, const int* in_sizes, int n_in,
                              void* d_out, int out_size, void* d_ws, size_t ws_size,
                              hipStream_t stream) {
  (void)in_sizes; (void)n_in; (void)out_size; (void)ws_size;
  const float* x  = (const float*)d_in[0];
  const float* wq = (const float*)d_in[1];
  const float* bq = (const float*)d_in[2];
  const float* wk = (const float*)d_in[3];
  const float* bk = (const float*)d_in[4];
  const float* wv = (const float*)d_in[5];
  const float* bv = (const float*)d_in[6];
  const float* wo = (const float*)d_in[7];
  float* out = (float*)d_out;

  char* ws = (char*)d_ws;
  u16*    xb    = (u16*)(ws);                       // 16,777,216 B
  u16*    wqkvT = (u16*)(ws + 16777216);            // 12,582,912
  u16*    woT   = (u16*)(ws + 29360128);            //  8,388,608
  float2* rtab  = (float2*)(ws + 37748736);         //  1,048,576
  u16*    qb    = (u16*)(ws + 38797312);            // 16,777,216 (tiled)
  u16*    kb    = (u16*)(ws + 55574528);            //  4,194,304 (tiled)
  u16*    vt    = (u16*)(ws + 59768832);            //  4,194,304 (tiled, PV-perm)
  u16*    ob    = (u16*)(ws + 63963136);            // 16,777,216  (total ~80.7 MB)

  float* outK = out + (size_t)BB * TT * DMODEL;
  float* outV = outK + (size_t)BB * NKV * TT * DH;

  cvt_x_kernel<<<8192, 256, 0, stream>>>(x, xb, (BB * TT * DMODEL) / 4);
  rope_table_kernel<<<512, 256, 0, stream>>>(rtab);
  transpose_cvt_kernel<<<dim3(32, 32), 256, 0, stream>>>(wq, wqkvT, 2048, 0);
  transpose_cvt_kernel<<<dim3(8, 32),  256, 0, stream>>>(wk, wqkvT, 512, 2048);
  transpose_cvt_kernel<<<dim3(8, 32),  256, 0, stream>>>(wv, wqkvT, 512, 2560);
  transpose_cvt_kernel<<<dim3(32, 32), 256, 0, stream>>>(wo, woT, 2048, 0);

  gemm_qkv_kernel<<<dim3(NQKV / 128, MM / 128), 256, 0, stream>>>(
      xb, wqkvT, bq, bk, bv, rtab, qb, kb, vt, outK, outV);

  attn_kernel<<<dim3(16, BB * NH), 256, 0, stream>>>(qb, kb, vt, ob);

  gemm_out_kernel<<<dim3(DMODEL / 128, MM / 128), 256, 0, stream>>>(
      ob, woT, out, MM, DMODEL, DMODEL);
}